// Round 8
// baseline (306.891 us; speedup 1.0000x reference)
//
#include <hip/hip_runtime.h>
#include <hip/hip_bf16.h>

// Problem constants (L,N,E,H,D) = (2048,4,512,8,64)
#define E_DIM 512
#define N_BATCH 4
#define L_SEQ 2048
#define N_HEADS 8
#define H_DIM 64
#define N_ROWS (L_SEQ * N_BATCH) /* 8192 */
#define EPS_F 1e-6f
#define SC_Q 0.18033688f  /* 0.125 * log2(e): scores come out in log2 space */

typedef __attribute__((ext_vector_type(8))) short bf16x8;
typedef __attribute__((ext_vector_type(8))) _Float16 f16x8;
typedef __attribute__((ext_vector_type(4))) float f32x4;
typedef __attribute__((ext_vector_type(16))) float f32x16;

__device__ __forceinline__ void split2(float f, __hip_bfloat16& h, __hip_bfloat16& l) {
  h = __float2bfloat16(f);
  l = __float2bfloat16(f - __bfloat162float(h));
}

__device__ __forceinline__ unsigned int packf16(float a, float b) {
  union { _Float16 h[2]; unsigned int u; } c;
  c.h[0] = (_Float16)a;  // RN casts: unbiased (RTZ pkrtz would bias softmax weights)
  c.h[1] = (_Float16)b;
  return c.u;
}

// ---------------------------------------------------------------------------
// Kernel W: pre-split weights fp32 -> bf16 hi/lo.  (wiolo now unused by proj
// but kept for layout stability; wohi/wolo feed out_proj.)
// ---------------------------------------------------------------------------
__global__ __launch_bounds__(256) void wconv_kernel(
    const float* __restrict__ wio, const float* __restrict__ wo,
    __hip_bfloat16* __restrict__ wiohi, __hip_bfloat16* __restrict__ wiolo,
    __hip_bfloat16* __restrict__ wohi, __hip_bfloat16* __restrict__ wolo) {
  const int g = blockIdx.x * 256 + threadIdx.x;
  const float* src;
  __hip_bfloat16 *dh, *dl;
  int i;
  if (g < 196608) { src = wio; dh = wiohi; dl = wiolo; i = g * 4; }
  else            { src = wo;  dh = wohi;  dl = wolo;  i = (g - 196608) * 4; }
  const float4 f = *(const float4*)(src + i);
  alignas(8) __hip_bfloat16 h[4], l[4];
  split2(f.x, h[0], l[0]); split2(f.y, h[1], l[1]);
  split2(f.z, h[2], l[2]); split2(f.w, h[3], l[3]);
  *(uint2*)(dh + i) = *(const uint2*)h;
  *(uint2*)(dl + i) = *(const uint2*)l;
}

// ---------------------------------------------------------------------------
// Kernel A: packed QKV projection via MFMA, hi/lo 2-pass (hh + lh; the hl
// term x_hi*w_lo is dropped -- its ~6e-4 q/k/v error attenuates to ~2e-5
// through attention).  Q epilogue folds the 0.125*log2e softmax scale and
// stores fp16; K stores fp16; V stores u = max(v+sh,eps)^p fp32.
// ---------------------------------------------------------------------------
__global__ __launch_bounds__(256, 3) void proj_qkv_kernel(
    const float* __restrict__ xq, const float* __restrict__ xk,
    const float* __restrict__ xv, const __hip_bfloat16* __restrict__ whi,
    const float* __restrict__ bias, const float* __restrict__ pw,
    const float* __restrict__ sw,
    _Float16* __restrict__ qbuf, _Float16* __restrict__ kbuf,
    float* __restrict__ ubuf) {
  __shared__ __hip_bfloat16 Xh[128][40];
  __shared__ __hip_bfloat16 Xl[128][40];
  __shared__ __hip_bfloat16 Wh[128][40];
  const int z = blockIdx.z;
  const int row0 = blockIdx.x * 128;
  const int col0 = blockIdx.y * 128;
  const float* __restrict__ xsrc = (z == 0) ? xq : (z == 1) ? xk : xv;
  const int tid = threadIdx.x;
  const int lane = tid & 63;
  const int wv = tid >> 6;
  const int lidx = lane & 15;
  const int quad = lane >> 4;
  const int srow = tid >> 1;
  const int scol = (tid & 1) * 16;

  f32x4 acc[2][8];
#pragma unroll
  for (int rt = 0; rt < 2; ++rt)
#pragma unroll
    for (int ct = 0; ct < 8; ++ct) acc[rt][ct] = (f32x4){0.f, 0.f, 0.f, 0.f};

  const int ar0 = wv * 32 + lidx;

  for (int kt = 0; kt < 16; ++kt) {
    const int k0 = kt * 32;
    {
      const float* xp = xsrc + (size_t)(row0 + srow) * E_DIM + k0 + scol;
      float f[16];
      *(float4*)&f[0]  = ((const float4*)xp)[0];
      *(float4*)&f[4]  = ((const float4*)xp)[1];
      *(float4*)&f[8]  = ((const float4*)xp)[2];
      *(float4*)&f[12] = ((const float4*)xp)[3];
      alignas(16) __hip_bfloat16 hi[16], lo[16];
#pragma unroll
      for (int j = 0; j < 16; ++j) split2(f[j], hi[j], lo[j]);
      *(uint4*)&Xh[srow][scol]     = ((const uint4*)hi)[0];
      *(uint4*)&Xh[srow][scol + 8] = ((const uint4*)hi)[1];
      *(uint4*)&Xl[srow][scol]     = ((const uint4*)lo)[0];
      *(uint4*)&Xl[srow][scol + 8] = ((const uint4*)lo)[1];
    }
    {
      const size_t wof = (size_t)(z * E_DIM + col0 + srow) * E_DIM + k0 + scol;
      *(uint4*)&Wh[srow][scol]     = ((const uint4*)(whi + wof))[0];
      *(uint4*)&Wh[srow][scol + 8] = ((const uint4*)(whi + wof))[1];
    }
    __syncthreads();

    const bf16x8 ah0 = *(const bf16x8*)&Xh[ar0][quad * 8];
    const bf16x8 ah1 = *(const bf16x8*)&Xh[ar0 + 16][quad * 8];
    const bf16x8 al0 = *(const bf16x8*)&Xl[ar0][quad * 8];
    const bf16x8 al1 = *(const bf16x8*)&Xl[ar0 + 16][quad * 8];
#pragma unroll
    for (int ct = 0; ct < 8; ++ct) {
      const bf16x8 bh = *(const bf16x8*)&Wh[ct * 16 + lidx][quad * 8];
      acc[0][ct] = __builtin_amdgcn_mfma_f32_16x16x32_bf16(ah0, bh, acc[0][ct], 0, 0, 0);
      acc[0][ct] = __builtin_amdgcn_mfma_f32_16x16x32_bf16(al0, bh, acc[0][ct], 0, 0, 0);
      acc[1][ct] = __builtin_amdgcn_mfma_f32_16x16x32_bf16(ah1, bh, acc[1][ct], 0, 0, 0);
      acc[1][ct] = __builtin_amdgcn_mfma_f32_16x16x32_bf16(al1, bh, acc[1][ct], 0, 0, 0);
    }
    __syncthreads();
  }

  if (z < 2) {
    _Float16* __restrict__ dst = (z == 0) ? qbuf : kbuf;
    const float scale = (z == 0) ? SC_Q : 1.0f;
    float bv[8];
#pragma unroll
    for (int ct = 0; ct < 8; ++ct) bv[ct] = bias[z * E_DIM + col0 + ct * 16 + lidx];
#pragma unroll
    for (int rt = 0; rt < 2; ++rt)
#pragma unroll
      for (int ct = 0; ct < 8; ++ct) {
        const int e = col0 + ct * 16 + lidx;
        const int h = e >> 6, d = e & 63;
#pragma unroll
        for (int reg = 0; reg < 4; ++reg) {
          const int R = row0 + wv * 32 + rt * 16 + quad * 4 + reg;
          const int lpos = R >> 2, nb = R & 3;
          dst[(((size_t)nb * N_HEADS + h) * L_SEQ + lpos) * H_DIM + d] =
              (_Float16)((acc[rt][ct][reg] + bv[ct]) * scale);
        }
      }
  } else {
    float bv[8], pv[8], sv[8];
#pragma unroll
    for (int ct = 0; ct < 8; ++ct) {
      const int e = col0 + ct * 16 + lidx;
      bv[ct] = bias[2 * E_DIM + e]; pv[ct] = pw[e]; sv[ct] = sw[e];
    }
#pragma unroll
    for (int rt = 0; rt < 2; ++rt)
#pragma unroll
      for (int ct = 0; ct < 8; ++ct) {
        const int e = col0 + ct * 16 + lidx;
        const int h = e >> 6, d = e & 63;
#pragma unroll
        for (int reg = 0; reg < 4; ++reg) {
          const int R = row0 + wv * 32 + rt * 16 + quad * 4 + reg;
          const int lpos = R >> 2, nb = R & 3;
          const float y = acc[rt][ct][reg] + bv[ct];
          const float vp = fmaxf(y + sv[ct], EPS_F);
          ubuf[(((size_t)nb * N_HEADS + h) * L_SEQ + lpos) * H_DIM + d] =
              __powf(vp, pv[ct]);
        }
      }
  }
}

// ---------------------------------------------------------------------------
// Kernel T: transpose u (n,h,l,d) fp32 -> u^T (n,h,d,l) fp16.
// ---------------------------------------------------------------------------
__global__ __launch_bounds__(256) void transp_kernel(
    const float* __restrict__ u, _Float16* __restrict__ uT) {
  __shared__ float T[64][65];
  const int lt = blockIdx.x, h = blockIdx.y, nb = blockIdx.z;
  const int tid = threadIdx.x;
  const int r = tid >> 2;
  const int cb = (tid & 3) * 16;
  const size_t srcbase = ((size_t)nb * N_HEADS + h) * L_SEQ + lt * 64;
  {
    const float* p = u + (srcbase + r) * H_DIM + cb;
    *(float4*)&T[r][cb + 0]  = ((const float4*)p)[0];
    *(float4*)&T[r][cb + 4]  = ((const float4*)p)[1];
    *(float4*)&T[r][cb + 8]  = ((const float4*)p)[2];
    *(float4*)&T[r][cb + 12] = ((const float4*)p)[3];
  }
  __syncthreads();
  alignas(16) _Float16 hv[16];
#pragma unroll
  for (int j = 0; j < 16; ++j) hv[j] = (_Float16)T[cb + j][r];
  const size_t dst = (((size_t)nb * N_HEADS + h) * H_DIM + r) * L_SEQ + lt * 64 + cb;
  *(uint4*)(uT + dst)     = ((const uint4*)hv)[0];
  *(uint4*)(uT + dst + 8) = ((const uint4*)hv)[1];
}

// ---------------------------------------------------------------------------
// Kernel B: fp16 MFMA flash attention, S^T orientation (A=K, B=Q) so P lives
// in registers in B-operand layout (q = lane&31): one shfl_xor(32) exchange
// replaces the LDS P round-trip.  O^T = U^T @ P^T; l = per-lane scalar sum.
//
// v8: v7's launch_bounds(256,4) demanded 4 waves/SIMD -> unified-file cap
// 128 total (VGPR_Count 64 + AGPRs) vs ~130 live -> spill (WRITE_SIZE
// 16->49MB, 98->127us).  The 64-q/1024-block TLP mechanism itself is sound
// (Occ did hit 32%).  v8 keeps it and fixes the register side:
//   (a) launch_bounds(256,3): allocator budget ~168 -- spill impossible for
//       this live set.  Residency follows ACTUAL compiled VGPR: if <=128 the
//       HW still schedules 4 blocks/CU (LDS 4x35.84=143KB fits); worst case
//       3 blocks/CU = 1.5x v6's TLP.
//   (b) peak-pressure halving: compute sc0 (s-rows 0..31) -> exp2/pack ->
//       then sc1 (s-rows 32..63) -> exp2/pack.  sc liveness 32->16 regs,
//       zero extra LDS traffic, same math (independent accumulators).
// Two-barrier single-buffer ordering verbatim from v3/v6/v7 (no prefetch).
// Grid (32,8,4) x 256 thr.
// ---------------------------------------------------------------------------
__global__ __launch_bounds__(256, 3) void attn_kernel(
    const _Float16* __restrict__ qbuf, const _Float16* __restrict__ kbuf,
    const _Float16* __restrict__ uT, const float* __restrict__ pw,
    const float* __restrict__ sw, __hip_bfloat16* __restrict__ ohhi,
    __hip_bfloat16* __restrict__ ohlo) {
  __shared__ union {
    struct { _Float16 Ks[128][72]; _Float16 Us[64][136]; } st;
    struct { float A[2][64][32]; float lA[2][64]; } red;
  } sm;
  const int qt = blockIdx.x, h = blockIdx.y, nb = blockIdx.z;
  const int q0 = qt * 64;
  const int tid = threadIdx.x;
  const int lane = tid & 63;
  const int w = tid >> 6;           // wave 0..3
  const int wv = w & 1;             // q-half (32 q each) of the 64-q block
  const int sg = w >> 1;            // s-group 0..1
  const int lm = lane & 31;
  const int kg = lane >> 5;         // k-group within MFMA operands
  const int srow = tid >> 1;        // K staging row 0..127
  const int scb = (tid & 1) * 32;   // K staging col base (fp16 units)
  const int urow = tid >> 2;        // U staging row (d) 0..63
  const int ucb = (tid & 3) * 32;   // U staging col base (s units)
  const size_t headbase = ((size_t)nb * N_HEADS + h) * L_SEQ;
  const size_t dbase = ((size_t)nb * N_HEADS + h) * H_DIM;

  // hoist Q B-frags straight from global (no Q LDS): q = q0 + wv*32 + lm
  f16x8 bq[4];
#pragma unroll
  for (int kc = 0; kc < 4; ++kc)
    bq[kc] = *(const f16x8*)(qbuf +
        (headbase + q0 + wv * 32 + lm) * H_DIM + kc * 16 + kg * 8);

  f32x16 o[2];  // [d-half mt2]
  o[0] = (f32x16)(0.f); o[1] = (f32x16)(0.f);
  float lsum = 0.f;

  for (int it = 0; it < 16; ++it) {
    const int s0 = it * 128;
    __syncthreads();  // B1: prior window's frag reads complete
    {
      const _Float16* kp = kbuf + (headbase + s0 + srow) * H_DIM + scb;
      *(uint4*)&sm.st.Ks[srow][scb + 0]  = ((const uint4*)kp)[0];
      *(uint4*)&sm.st.Ks[srow][scb + 8]  = ((const uint4*)kp)[1];
      *(uint4*)&sm.st.Ks[srow][scb + 16] = ((const uint4*)kp)[2];
      *(uint4*)&sm.st.Ks[srow][scb + 24] = ((const uint4*)kp)[3];
      const _Float16* up = uT + (dbase + urow) * L_SEQ + s0 + ucb;
      *(uint4*)&sm.st.Us[urow][ucb + 0]  = ((const uint4*)up)[0];
      *(uint4*)&sm.st.Us[urow][ucb + 8]  = ((const uint4*)up)[1];
      *(uint4*)&sm.st.Us[urow][ucb + 16] = ((const uint4*)up)[2];
      *(uint4*)&sm.st.Us[urow][ucb + 24] = ((const uint4*)up)[3];
    }
    __syncthreads();  // B2: staged tile visible to all waves

    const int sr = sg * 64;  // this wave's s-rows within the staged 128
    unsigned int P2[2][4][2];

    // ---- S^T phase A: sc0 over s-rows sr..sr+31; exp2/pack into P2[0] ----
    {
      f32x16 sc0 = (f32x16)(0.f);
#pragma unroll
      for (int kc = 0; kc < 4; ++kc) {
        const f16x8 ak0 = *(const f16x8*)&sm.st.Ks[sr + lm][kc * 16 + kg * 8];
        sc0 = __builtin_amdgcn_mfma_f32_32x32x16_f16(ak0, bq[kc], sc0, 0, 0, 0);
      }
#pragma unroll
      for (int g = 0; g < 4; ++g) {
        const float p0 = __builtin_amdgcn_exp2f(sc0[4 * g + 0]);
        const float p1 = __builtin_amdgcn_exp2f(sc0[4 * g + 1]);
        const float p2 = __builtin_amdgcn_exp2f(sc0[4 * g + 2]);
        const float p3 = __builtin_amdgcn_exp2f(sc0[4 * g + 3]);
        lsum += (p0 + p1) + (p2 + p3);
        P2[0][g][0] = packf16(p0, p1);
        P2[0][g][1] = packf16(p2, p3);
      }
    }
    // ---- S^T phase B: sc1 over s-rows sr+32..sr+63; pack into P2[1] ----
    {
      f32x16 sc1 = (f32x16)(0.f);
#pragma unroll
      for (int kc = 0; kc < 4; ++kc) {
        const f16x8 ak1 = *(const f16x8*)&sm.st.Ks[sr + 32 + lm][kc * 16 + kg * 8];
        sc1 = __builtin_amdgcn_mfma_f32_32x32x16_f16(ak1, bq[kc], sc1, 0, 0, 0);
      }
#pragma unroll
      for (int g = 0; g < 4; ++g) {
        const float p0 = __builtin_amdgcn_exp2f(sc1[4 * g + 0]);
        const float p1 = __builtin_amdgcn_exp2f(sc1[4 * g + 1]);
        const float p2 = __builtin_amdgcn_exp2f(sc1[4 * g + 2]);
        const float p3 = __builtin_amdgcn_exp2f(sc1[4 * g + 3]);
        lsum += (p0 + p1) + (p2 + p3);
        P2[1][g][0] = packf16(p0, p1);
        P2[1][g][1] = packf16(p2, p3);
      }
    }

    // ---- PV: O^T += U^T @ P^T; P B-frags via xor-32 exchange ----
#pragma unroll
    for (int kc = 0; kc < 4; ++kc) {
      const int mt = kc >> 1;
      const f16x8 au0 = *(const f16x8*)&sm.st.Us[lm][sr + kc * 16 + kg * 8];
      const f16x8 au1 = *(const f16x8*)&sm.st.Us[32 + lm][sr + kc * 16 + kg * 8];
      const int gx = (2 * kc) & 3, gy = (2 * kc + 1) & 3;
      const unsigned int x0 = P2[mt][gx][0], x1 = P2[mt][gx][1];
      const unsigned int y0 = P2[mt][gy][0], y1 = P2[mt][gy][1];
      const unsigned int sA = kg ? x0 : y0, sB = kg ? x1 : y1;
      const unsigned int rA = (unsigned int)__shfl_xor((int)sA, 32);
      const unsigned int rB = (unsigned int)__shfl_xor((int)sB, 32);
      union { unsigned int u[4]; f16x8 v; } bp;
      bp.u[0] = kg ? rA : x0;  // j0..3: s = kc*16+kg*8+0..3
      bp.u[1] = kg ? rB : x1;
      bp.u[2] = kg ? y0 : rA;  // j4..7: s = kc*16+kg*8+4..7
      bp.u[3] = kg ? y1 : rB;
      o[0] = __builtin_amdgcn_mfma_f32_32x32x16_f16(au0, bp.v, o[0], 0, 0, 0);
      o[1] = __builtin_amdgcn_mfma_f32_32x32x16_f16(au1, bp.v, o[1], 0, 0, 0);
    }
  }

  // ---- cross-s-group reduction in LDS: sg1 publishes (o, lsum), sg0
  //      accumulates.  XOR-swizzled float4 slots (8 slots over lane&7). ----
  float* redA = &sm.red.A[0][0][0];
  float* lrA = &sm.red.lA[0][0];

  __syncthreads();  // loop's trailing frag reads complete before LDS reuse
  if (sg == 1) {
    lrA[wv * 64 + lane] = lsum;
#pragma unroll
    for (int mt2 = 0; mt2 < 2; ++mt2)
#pragma unroll
      for (int g = 0; g < 4; ++g) {
        const int i4 = (mt2 * 4 + g) ^ (lane & 7);
        float4 v = {o[mt2][4 * g + 0], o[mt2][4 * g + 1],
                    o[mt2][4 * g + 2], o[mt2][4 * g + 3]};
        *(float4*)(redA + ((size_t)(wv * 64 + lane)) * 32 + i4 * 4) = v;
      }
  }
  __syncthreads();
  if (sg == 1) return;  // sg0 past this point; no further barriers
  lsum += lrA[wv * 64 + lane];
#pragma unroll
  for (int mt2 = 0; mt2 < 2; ++mt2)
#pragma unroll
    for (int g = 0; g < 4; ++g) {
      const int i4 = (mt2 * 4 + g) ^ (lane & 7);
      const float4 v =
          *(const float4*)(redA + ((size_t)(wv * 64 + lane)) * 32 + i4 * 4);
      o[mt2][4 * g + 0] += v.x; o[mt2][4 * g + 1] += v.y;
      o[mt2][4 * g + 2] += v.z; o[mt2][4 * g + 3] += v.w;
    }

  // ---- epilogue: finish l across kg halves, GeM inverse, packed stores ----
  {
    const float l = lsum + __shfl_xor(lsum, 32);
    const float inv = 1.0f / l;
    const int qg = q0 + wv * 32 + lm;
    const size_t base = ((size_t)qg * N_BATCH + nb) * E_DIM + h * H_DIM;
#pragma unroll
    for (int mt2 = 0; mt2 < 2; ++mt2)
#pragma unroll
      for (int g = 0; g < 4; ++g) {
        alignas(8) __hip_bfloat16 hb[4], lb[4];
#pragma unroll
        for (int i = 0; i < 4; ++i) {
          const int d = mt2 * 32 + 8 * g + 4 * kg + i;
          const int e = h * H_DIM + d;
          const float pooled = o[mt2][4 * g + i] * inv;
          const float val = __powf(fmaxf(pooled, EPS_F), 1.0f / pw[e]) - sw[e];
          split2(val, hb[i], lb[i]);
        }
        const int d0 = mt2 * 32 + 8 * g + 4 * kg;
        *(uint2*)(ohhi + base + d0) = *(const uint2*)hb;
        *(uint2*)(ohlo + base + d0) = *(const uint2*)lb;
      }
  }
}

// ---------------------------------------------------------------------------
// Kernel C: output projection via MFMA, hi/lo 3-pass.  (unchanged)
// ---------------------------------------------------------------------------
__global__ __launch_bounds__(256, 4) void out_proj_kernel(
    const __hip_bfloat16* __restrict__ xhi, const __hip_bfloat16* __restrict__ xlo,
    const __hip_bfloat16* __restrict__ whi, const __hip_bfloat16* __restrict__ wlo,
    const float* __restrict__ bias, float* __restrict__ out) {
  __shared__ __hip_bfloat16 Xh[128][40];
  __shared__ __hip_bfloat16 Xl[128][40];
  __shared__ __hip_bfloat16 Wh[64][40];
  __shared__ __hip_bfloat16 Wl[64][40];
  const int row0 = blockIdx.x * 128;
  const int col0 = blockIdx.y * 64;
  const int tid = threadIdx.x;
  const int lane = tid & 63;
  const int wv = tid >> 6;
  const int lidx = lane & 15;
  const int quad = lane >> 4;
  const int srow = tid >> 1;
  const int scol = (tid & 1) * 16;
  const int wrow = tid >> 2;
  const int wcol = (tid & 3) * 8;

  f32x4 acc[2][4];
#pragma unroll
  for (int rt = 0; rt < 2; ++rt)
#pragma unroll
    for (int ct = 0; ct < 4; ++ct) acc[rt][ct] = (f32x4){0.f, 0.f, 0.f, 0.f};

  const int ar0 = wv * 32 + lidx;

  for (int kt = 0; kt < 16; ++kt) {
    const int k0 = kt * 32;
    {
      const size_t xof = (size_t)(row0 + srow) * E_DIM + k0 + scol;
      *(uint4*)&Xh[srow][scol]     = ((const uint4*)(xhi + xof))[0];
      *(uint4*)&Xh[srow][scol + 8] = ((const uint4*)(xhi + xof))[1];
      *(uint4*)&Xl[srow][scol]     = ((const uint4*)(xlo + xof))[0];
      *(uint4*)&Xl[srow][scol + 8] = ((const uint4*)(xlo + xof))[1];
      const size_t wof = (size_t)(col0 + wrow) * E_DIM + k0 + wcol;
      *(uint4*)&Wh[wrow][wcol] = *(const uint4*)(whi + wof);
      *(uint4*)&Wl[wrow][wcol] = *(const uint4*)(wlo + wof);
    }
    __syncthreads();

    const bf16x8 ah0 = *(const bf16x8*)&Xh[ar0][quad * 8];
    const bf16x8 ah1 = *(const bf16x8*)&Xh[ar0 + 16][quad * 8];
    const bf16x8 al0 = *(const bf16x8*)&Xl[ar0][quad * 8];
    const bf16x8 al1 = *(const bf16x8*)&Xl[ar0 + 16][quad * 8];
#pragma unroll
    for (int ct = 0; ct < 4; ++ct) {
      const bf16x8 bh = *(const bf16x8*)&Wh[ct * 16 + lidx][quad * 8];
      const bf16x8 bl = *(const bf16x8*)&Wl[ct * 16 + lidx][quad * 8];
      acc[0][ct] = __builtin_amdgcn_mfma_f32_16x16x32_bf16(ah0, bh, acc[0][ct], 0, 0, 0);
      acc[0][ct] = __builtin_amdgcn_mfma_f32_16x16x32_bf16(al0, bh, acc[0][ct], 0, 0, 0);
      acc[0][ct] = __builtin_amdgcn_mfma_f32_16x16x32_bf16(ah0, bl, acc[0][ct], 0, 0, 0);
      acc[1][ct] = __builtin_amdgcn_mfma_f32_16x16x32_bf16(ah1, bh, acc[1][ct], 0, 0, 0);
      acc[1][ct] = __builtin_amdgcn_mfma_f32_16x16x32_bf16(al1, bh, acc[1][ct], 0, 0, 0);
      acc[1][ct] = __builtin_amdgcn_mfma_f32_16x16x32_bf16(ah1, bl, acc[1][ct], 0, 0, 0);
    }
    __syncthreads();
  }

  float bv[4];
#pragma unroll
  for (int ct = 0; ct < 4; ++ct) bv[ct] = bias[col0 + ct * 16 + lidx];
#pragma unroll
  for (int rt = 0; rt < 2; ++rt)
#pragma unroll
    for (int ct = 0; ct < 4; ++ct) {
      const int c = col0 + ct * 16 + lidx;
#pragma unroll
      for (int reg = 0; reg < 4; ++reg) {
        const int R = row0 + wv * 32 + rt * 16 + quad * 4 + reg;
        out[(size_t)R * E_DIM + c] = acc[rt][ct][reg] + bv[ct];
      }
    }
}

extern "C" void kernel_launch(void* const* d_in, const int* in_sizes, int n_in,
                              void* d_out, int out_size, void* d_ws, size_t ws_size,
                              hipStream_t stream) {
  const float* q_in = (const float*)d_in[0];
  const float* k_in = (const float*)d_in[1];
  const float* v_in = (const float*)d_in[2];
  const float* wio  = (const float*)d_in[3];
  const float* bio  = (const float*)d_in[4];
  const float* wo   = (const float*)d_in[5];
  const float* bo   = (const float*)d_in[6];
  const float* pw   = (const float*)d_in[7];
  const float* sw   = (const float*)d_in[8];

  // Workspace: qbuf,kbuf f16 (8 MiB ea); ubuf fp32 16 MiB (reused as
  // ohhi/ohlo bf16 8+8 after transp); uT f16 8 MiB; weight splits ~4 MiB.
  const size_t NE = (size_t)N_ROWS * E_DIM;
  _Float16* qbuf = (_Float16*)d_ws;
  _Float16* kbuf = qbuf + NE;
  float* ubuf = (float*)(kbuf + NE);
  _Float16* uT = (_Float16*)(ubuf + NE);
  __hip_bfloat16* wiohi = (__hip_bfloat16*)(uT + NE);
  __hip_bfloat16* wiolo = wiohi + 786432;
  __hip_bfloat16* wohi  = wiolo + 786432;
  __hip_bfloat16* wolo  = wohi + 262144;
  __hip_bfloat16* ohhi = (__hip_bfloat16*)ubuf;  // alias: ubuf dead after transp
  __hip_bfloat16* ohlo = ohhi + NE;

  wconv_kernel<<<dim3(1024), 256, 0, stream>>>(wio, wo, wiohi, wiolo, wohi, wolo);
  proj_qkv_kernel<<<dim3(64, 4, 3), 256, 0, stream>>>(q_in, k_in, v_in, wiohi,
                                                      bio, pw, sw, qbuf, kbuf, ubuf);
  transp_kernel<<<dim3(32, 8, 4), 256, 0, stream>>>(ubuf, uT);
  attn_kernel<<<dim3(32, 8, 4), 256, 0, stream>>>(qbuf, kbuf, uT, pw, sw,
                                                  ohhi, ohlo);
  out_proj_kernel<<<dim3(64, 8), 256, 0, stream>>>(ohhi, ohlo, wohi, wolo,
                                                   bo, (float*)d_out);
}

// Round 9
// 291.276 us; speedup vs baseline: 1.0536x; 1.0536x over previous
//
#include <hip/hip_runtime.h>
#include <hip/hip_bf16.h>

// Problem constants (L,N,E,H,D) = (2048,4,512,8,64)
#define E_DIM 512
#define N_BATCH 4
#define L_SEQ 2048
#define N_HEADS 8
#define H_DIM 64
#define N_ROWS (L_SEQ * N_BATCH) /* 8192 */
#define EPS_F 1e-6f
#define SC_Q 0.18033688f  /* 0.125 * log2(e): scores come out in log2 space */

typedef __attribute__((ext_vector_type(8))) short bf16x8;
typedef __attribute__((ext_vector_type(8))) _Float16 f16x8;
typedef __attribute__((ext_vector_type(4))) float f32x4;
typedef __attribute__((ext_vector_type(16))) float f32x16;

__device__ __forceinline__ void split2(float f, __hip_bfloat16& h, __hip_bfloat16& l) {
  h = __float2bfloat16(f);
  l = __float2bfloat16(f - __bfloat162float(h));
}

__device__ __forceinline__ unsigned int packf16(float a, float b) {
  union { _Float16 h[2]; unsigned int u; } c;
  c.h[0] = (_Float16)a;  // RN casts: unbiased (RTZ pkrtz would bias softmax weights)
  c.h[1] = (_Float16)b;
  return c.u;
}

// ---------------------------------------------------------------------------
// Kernel W: pre-split weights fp32 -> bf16 hi/lo.  (wiolo now unused by proj
// but kept for layout stability; wohi/wolo feed out_proj.)
// ---------------------------------------------------------------------------
__global__ __launch_bounds__(256) void wconv_kernel(
    const float* __restrict__ wio, const float* __restrict__ wo,
    __hip_bfloat16* __restrict__ wiohi, __hip_bfloat16* __restrict__ wiolo,
    __hip_bfloat16* __restrict__ wohi, __hip_bfloat16* __restrict__ wolo) {
  const int g = blockIdx.x * 256 + threadIdx.x;
  const float* src;
  __hip_bfloat16 *dh, *dl;
  int i;
  if (g < 196608) { src = wio; dh = wiohi; dl = wiolo; i = g * 4; }
  else            { src = wo;  dh = wohi;  dl = wolo;  i = (g - 196608) * 4; }
  const float4 f = *(const float4*)(src + i);
  alignas(8) __hip_bfloat16 h[4], l[4];
  split2(f.x, h[0], l[0]); split2(f.y, h[1], l[1]);
  split2(f.z, h[2], l[2]); split2(f.w, h[3], l[3]);
  *(uint2*)(dh + i) = *(const uint2*)h;
  *(uint2*)(dl + i) = *(const uint2*)l;
}

// ---------------------------------------------------------------------------
// Kernel A: packed QKV projection via MFMA, hi/lo 2-pass (hh + lh; the hl
// term x_hi*w_lo is dropped -- its ~6e-4 q/k/v error attenuates to ~2e-5
// through attention).  Q epilogue folds the 0.125*log2e softmax scale and
// stores fp16; K stores fp16; V stores u = max(v+sh,eps)^p fp32.
// ---------------------------------------------------------------------------
__global__ __launch_bounds__(256, 3) void proj_qkv_kernel(
    const float* __restrict__ xq, const float* __restrict__ xk,
    const float* __restrict__ xv, const __hip_bfloat16* __restrict__ whi,
    const float* __restrict__ bias, const float* __restrict__ pw,
    const float* __restrict__ sw,
    _Float16* __restrict__ qbuf, _Float16* __restrict__ kbuf,
    float* __restrict__ ubuf) {
  __shared__ __hip_bfloat16 Xh[128][40];
  __shared__ __hip_bfloat16 Xl[128][40];
  __shared__ __hip_bfloat16 Wh[128][40];
  const int z = blockIdx.z;
  const int row0 = blockIdx.x * 128;
  const int col0 = blockIdx.y * 128;
  const float* __restrict__ xsrc = (z == 0) ? xq : (z == 1) ? xk : xv;
  const int tid = threadIdx.x;
  const int lane = tid & 63;
  const int wv = tid >> 6;
  const int lidx = lane & 15;
  const int quad = lane >> 4;
  const int srow = tid >> 1;
  const int scol = (tid & 1) * 16;

  f32x4 acc[2][8];
#pragma unroll
  for (int rt = 0; rt < 2; ++rt)
#pragma unroll
    for (int ct = 0; ct < 8; ++ct) acc[rt][ct] = (f32x4){0.f, 0.f, 0.f, 0.f};

  const int ar0 = wv * 32 + lidx;

  for (int kt = 0; kt < 16; ++kt) {
    const int k0 = kt * 32;
    {
      const float* xp = xsrc + (size_t)(row0 + srow) * E_DIM + k0 + scol;
      float f[16];
      *(float4*)&f[0]  = ((const float4*)xp)[0];
      *(float4*)&f[4]  = ((const float4*)xp)[1];
      *(float4*)&f[8]  = ((const float4*)xp)[2];
      *(float4*)&f[12] = ((const float4*)xp)[3];
      alignas(16) __hip_bfloat16 hi[16], lo[16];
#pragma unroll
      for (int j = 0; j < 16; ++j) split2(f[j], hi[j], lo[j]);
      *(uint4*)&Xh[srow][scol]     = ((const uint4*)hi)[0];
      *(uint4*)&Xh[srow][scol + 8] = ((const uint4*)hi)[1];
      *(uint4*)&Xl[srow][scol]     = ((const uint4*)lo)[0];
      *(uint4*)&Xl[srow][scol + 8] = ((const uint4*)lo)[1];
    }
    {
      const size_t wof = (size_t)(z * E_DIM + col0 + srow) * E_DIM + k0 + scol;
      *(uint4*)&Wh[srow][scol]     = ((const uint4*)(whi + wof))[0];
      *(uint4*)&Wh[srow][scol + 8] = ((const uint4*)(whi + wof))[1];
    }
    __syncthreads();

    const bf16x8 ah0 = *(const bf16x8*)&Xh[ar0][quad * 8];
    const bf16x8 ah1 = *(const bf16x8*)&Xh[ar0 + 16][quad * 8];
    const bf16x8 al0 = *(const bf16x8*)&Xl[ar0][quad * 8];
    const bf16x8 al1 = *(const bf16x8*)&Xl[ar0 + 16][quad * 8];
#pragma unroll
    for (int ct = 0; ct < 8; ++ct) {
      const bf16x8 bh = *(const bf16x8*)&Wh[ct * 16 + lidx][quad * 8];
      acc[0][ct] = __builtin_amdgcn_mfma_f32_16x16x32_bf16(ah0, bh, acc[0][ct], 0, 0, 0);
      acc[0][ct] = __builtin_amdgcn_mfma_f32_16x16x32_bf16(al0, bh, acc[0][ct], 0, 0, 0);
      acc[1][ct] = __builtin_amdgcn_mfma_f32_16x16x32_bf16(ah1, bh, acc[1][ct], 0, 0, 0);
      acc[1][ct] = __builtin_amdgcn_mfma_f32_16x16x32_bf16(al1, bh, acc[1][ct], 0, 0, 0);
    }
    __syncthreads();
  }

  if (z < 2) {
    _Float16* __restrict__ dst = (z == 0) ? qbuf : kbuf;
    const float scale = (z == 0) ? SC_Q : 1.0f;
    float bv[8];
#pragma unroll
    for (int ct = 0; ct < 8; ++ct) bv[ct] = bias[z * E_DIM + col0 + ct * 16 + lidx];
#pragma unroll
    for (int rt = 0; rt < 2; ++rt)
#pragma unroll
      for (int ct = 0; ct < 8; ++ct) {
        const int e = col0 + ct * 16 + lidx;
        const int h = e >> 6, d = e & 63;
#pragma unroll
        for (int reg = 0; reg < 4; ++reg) {
          const int R = row0 + wv * 32 + rt * 16 + quad * 4 + reg;
          const int lpos = R >> 2, nb = R & 3;
          dst[(((size_t)nb * N_HEADS + h) * L_SEQ + lpos) * H_DIM + d] =
              (_Float16)((acc[rt][ct][reg] + bv[ct]) * scale);
        }
      }
  } else {
    float bv[8], pv[8], sv[8];
#pragma unroll
    for (int ct = 0; ct < 8; ++ct) {
      const int e = col0 + ct * 16 + lidx;
      bv[ct] = bias[2 * E_DIM + e]; pv[ct] = pw[e]; sv[ct] = sw[e];
    }
#pragma unroll
    for (int rt = 0; rt < 2; ++rt)
#pragma unroll
      for (int ct = 0; ct < 8; ++ct) {
        const int e = col0 + ct * 16 + lidx;
        const int h = e >> 6, d = e & 63;
#pragma unroll
        for (int reg = 0; reg < 4; ++reg) {
          const int R = row0 + wv * 32 + rt * 16 + quad * 4 + reg;
          const int lpos = R >> 2, nb = R & 3;
          const float y = acc[rt][ct][reg] + bv[ct];
          const float vp = fmaxf(y + sv[ct], EPS_F);
          ubuf[(((size_t)nb * N_HEADS + h) * L_SEQ + lpos) * H_DIM + d] =
              __powf(vp, pv[ct]);
        }
      }
  }
}

// ---------------------------------------------------------------------------
// Kernel T: transpose u (n,h,l,d) fp32 -> u^T (n,h,d,l) fp16.
// ---------------------------------------------------------------------------
__global__ __launch_bounds__(256) void transp_kernel(
    const float* __restrict__ u, _Float16* __restrict__ uT) {
  __shared__ float T[64][65];
  const int lt = blockIdx.x, h = blockIdx.y, nb = blockIdx.z;
  const int tid = threadIdx.x;
  const int r = tid >> 2;
  const int cb = (tid & 3) * 16;
  const size_t srcbase = ((size_t)nb * N_HEADS + h) * L_SEQ + lt * 64;
  {
    const float* p = u + (srcbase + r) * H_DIM + cb;
    *(float4*)&T[r][cb + 0]  = ((const float4*)p)[0];
    *(float4*)&T[r][cb + 4]  = ((const float4*)p)[1];
    *(float4*)&T[r][cb + 8]  = ((const float4*)p)[2];
    *(float4*)&T[r][cb + 12] = ((const float4*)p)[3];
  }
  __syncthreads();
  alignas(16) _Float16 hv[16];
#pragma unroll
  for (int j = 0; j < 16; ++j) hv[j] = (_Float16)T[cb + j][r];
  const size_t dst = (((size_t)nb * N_HEADS + h) * H_DIM + r) * L_SEQ + lt * 64 + cb;
  *(uint4*)(uT + dst)     = ((const uint4*)hv)[0];
  *(uint4*)(uT + dst + 8) = ((const uint4*)hv)[1];
}

// ---------------------------------------------------------------------------
// Kernel B: fp16 MFMA flash attention, S^T orientation (A=K, B=Q) so P lives
// in registers in B-operand layout (q = lane&31): one shfl_xor(32) exchange
// replaces the LDS P round-trip.  O^T = U^T @ P^T; l = per-lane scalar sum.
//
// v9: v7/v8 proved the 64-q/1024-block TLP works (Occ 2x) but BOTH tightened
// launch_bounds ((256,4)/(256,3)) and both spilled: the 2nd arg is a MINIMUM
// waves/EU -- the compiler's occupancy heuristic targets MORE waves and
// shrinks the budget below the live set (VGPR_Count 64/68 + 19-33MB scratch
// writes).  The two healthy compiles (v3: 116 regs, v6: 124 regs, 0 spill)
// were both at (256,2).  v9 = v8's exact structure (64-q tile, phase-split
// sc, 128-row window, two-barrier ordering) with launch_bounds(256,2):
// budget 256 -> no spill; HW residency follows ACTUAL compiled count
// (~90-110 expected): <=128 -> 4 blocks/CU (LDS 4x35.84=143KB fits, grid
// 1024 supplies them); 129-170 -> 3 blocks/CU.  Either >= 1.5x v6's TLP.
// Check first: WRITE_SIZE ~16.5MB (no spill signature).
// Grid (32,8,4) x 256 thr.
// ---------------------------------------------------------------------------
__global__ __launch_bounds__(256, 2) void attn_kernel(
    const _Float16* __restrict__ qbuf, const _Float16* __restrict__ kbuf,
    const _Float16* __restrict__ uT, const float* __restrict__ pw,
    const float* __restrict__ sw, __hip_bfloat16* __restrict__ ohhi,
    __hip_bfloat16* __restrict__ ohlo) {
  __shared__ union {
    struct { _Float16 Ks[128][72]; _Float16 Us[64][136]; } st;
    struct { float A[2][64][32]; float lA[2][64]; } red;
  } sm;
  const int qt = blockIdx.x, h = blockIdx.y, nb = blockIdx.z;
  const int q0 = qt * 64;
  const int tid = threadIdx.x;
  const int lane = tid & 63;
  const int w = tid >> 6;           // wave 0..3
  const int wv = w & 1;             // q-half (32 q each) of the 64-q block
  const int sg = w >> 1;            // s-group 0..1
  const int lm = lane & 31;
  const int kg = lane >> 5;         // k-group within MFMA operands
  const int srow = tid >> 1;        // K staging row 0..127
  const int scb = (tid & 1) * 32;   // K staging col base (fp16 units)
  const int urow = tid >> 2;        // U staging row (d) 0..63
  const int ucb = (tid & 3) * 32;   // U staging col base (s units)
  const size_t headbase = ((size_t)nb * N_HEADS + h) * L_SEQ;
  const size_t dbase = ((size_t)nb * N_HEADS + h) * H_DIM;

  // hoist Q B-frags straight from global (no Q LDS): q = q0 + wv*32 + lm
  f16x8 bq[4];
#pragma unroll
  for (int kc = 0; kc < 4; ++kc)
    bq[kc] = *(const f16x8*)(qbuf +
        (headbase + q0 + wv * 32 + lm) * H_DIM + kc * 16 + kg * 8);

  f32x16 o[2];  // [d-half mt2]
  o[0] = (f32x16)(0.f); o[1] = (f32x16)(0.f);
  float lsum = 0.f;

  for (int it = 0; it < 16; ++it) {
    const int s0 = it * 128;
    __syncthreads();  // B1: prior window's frag reads complete
    {
      const _Float16* kp = kbuf + (headbase + s0 + srow) * H_DIM + scb;
      *(uint4*)&sm.st.Ks[srow][scb + 0]  = ((const uint4*)kp)[0];
      *(uint4*)&sm.st.Ks[srow][scb + 8]  = ((const uint4*)kp)[1];
      *(uint4*)&sm.st.Ks[srow][scb + 16] = ((const uint4*)kp)[2];
      *(uint4*)&sm.st.Ks[srow][scb + 24] = ((const uint4*)kp)[3];
      const _Float16* up = uT + (dbase + urow) * L_SEQ + s0 + ucb;
      *(uint4*)&sm.st.Us[urow][ucb + 0]  = ((const uint4*)up)[0];
      *(uint4*)&sm.st.Us[urow][ucb + 8]  = ((const uint4*)up)[1];
      *(uint4*)&sm.st.Us[urow][ucb + 16] = ((const uint4*)up)[2];
      *(uint4*)&sm.st.Us[urow][ucb + 24] = ((const uint4*)up)[3];
    }
    __syncthreads();  // B2: staged tile visible to all waves

    const int sr = sg * 64;  // this wave's s-rows within the staged 128
    unsigned int P2[2][4][2];

    // ---- S^T phase A: sc0 over s-rows sr..sr+31; exp2/pack into P2[0] ----
    {
      f32x16 sc0 = (f32x16)(0.f);
#pragma unroll
      for (int kc = 0; kc < 4; ++kc) {
        const f16x8 ak0 = *(const f16x8*)&sm.st.Ks[sr + lm][kc * 16 + kg * 8];
        sc0 = __builtin_amdgcn_mfma_f32_32x32x16_f16(ak0, bq[kc], sc0, 0, 0, 0);
      }
#pragma unroll
      for (int g = 0; g < 4; ++g) {
        const float p0 = __builtin_amdgcn_exp2f(sc0[4 * g + 0]);
        const float p1 = __builtin_amdgcn_exp2f(sc0[4 * g + 1]);
        const float p2 = __builtin_amdgcn_exp2f(sc0[4 * g + 2]);
        const float p3 = __builtin_amdgcn_exp2f(sc0[4 * g + 3]);
        lsum += (p0 + p1) + (p2 + p3);
        P2[0][g][0] = packf16(p0, p1);
        P2[0][g][1] = packf16(p2, p3);
      }
    }
    // ---- S^T phase B: sc1 over s-rows sr+32..sr+63; pack into P2[1] ----
    {
      f32x16 sc1 = (f32x16)(0.f);
#pragma unroll
      for (int kc = 0; kc < 4; ++kc) {
        const f16x8 ak1 = *(const f16x8*)&sm.st.Ks[sr + 32 + lm][kc * 16 + kg * 8];
        sc1 = __builtin_amdgcn_mfma_f32_32x32x16_f16(ak1, bq[kc], sc1, 0, 0, 0);
      }
#pragma unroll
      for (int g = 0; g < 4; ++g) {
        const float p0 = __builtin_amdgcn_exp2f(sc1[4 * g + 0]);
        const float p1 = __builtin_amdgcn_exp2f(sc1[4 * g + 1]);
        const float p2 = __builtin_amdgcn_exp2f(sc1[4 * g + 2]);
        const float p3 = __builtin_amdgcn_exp2f(sc1[4 * g + 3]);
        lsum += (p0 + p1) + (p2 + p3);
        P2[1][g][0] = packf16(p0, p1);
        P2[1][g][1] = packf16(p2, p3);
      }
    }

    // ---- PV: O^T += U^T @ P^T; P B-frags via xor-32 exchange ----
#pragma unroll
    for (int kc = 0; kc < 4; ++kc) {
      const int mt = kc >> 1;
      const f16x8 au0 = *(const f16x8*)&sm.st.Us[lm][sr + kc * 16 + kg * 8];
      const f16x8 au1 = *(const f16x8*)&sm.st.Us[32 + lm][sr + kc * 16 + kg * 8];
      const int gx = (2 * kc) & 3, gy = (2 * kc + 1) & 3;
      const unsigned int x0 = P2[mt][gx][0], x1 = P2[mt][gx][1];
      const unsigned int y0 = P2[mt][gy][0], y1 = P2[mt][gy][1];
      const unsigned int sA = kg ? x0 : y0, sB = kg ? x1 : y1;
      const unsigned int rA = (unsigned int)__shfl_xor((int)sA, 32);
      const unsigned int rB = (unsigned int)__shfl_xor((int)sB, 32);
      union { unsigned int u[4]; f16x8 v; } bp;
      bp.u[0] = kg ? rA : x0;  // j0..3: s = kc*16+kg*8+0..3
      bp.u[1] = kg ? rB : x1;
      bp.u[2] = kg ? y0 : rA;  // j4..7: s = kc*16+kg*8+4..7
      bp.u[3] = kg ? y1 : rB;
      o[0] = __builtin_amdgcn_mfma_f32_32x32x16_f16(au0, bp.v, o[0], 0, 0, 0);
      o[1] = __builtin_amdgcn_mfma_f32_32x32x16_f16(au1, bp.v, o[1], 0, 0, 0);
    }
  }

  // ---- cross-s-group reduction in LDS: sg1 publishes (o, lsum), sg0
  //      accumulates.  XOR-swizzled float4 slots (8 slots over lane&7). ----
  float* redA = &sm.red.A[0][0][0];
  float* lrA = &sm.red.lA[0][0];

  __syncthreads();  // loop's trailing frag reads complete before LDS reuse
  if (sg == 1) {
    lrA[wv * 64 + lane] = lsum;
#pragma unroll
    for (int mt2 = 0; mt2 < 2; ++mt2)
#pragma unroll
      for (int g = 0; g < 4; ++g) {
        const int i4 = (mt2 * 4 + g) ^ (lane & 7);
        float4 v = {o[mt2][4 * g + 0], o[mt2][4 * g + 1],
                    o[mt2][4 * g + 2], o[mt2][4 * g + 3]};
        *(float4*)(redA + ((size_t)(wv * 64 + lane)) * 32 + i4 * 4) = v;
      }
  }
  __syncthreads();
  if (sg == 1) return;  // sg0 past this point; no further barriers
  lsum += lrA[wv * 64 + lane];
#pragma unroll
  for (int mt2 = 0; mt2 < 2; ++mt2)
#pragma unroll
    for (int g = 0; g < 4; ++g) {
      const int i4 = (mt2 * 4 + g) ^ (lane & 7);
      const float4 v =
          *(const float4*)(redA + ((size_t)(wv * 64 + lane)) * 32 + i4 * 4);
      o[mt2][4 * g + 0] += v.x; o[mt2][4 * g + 1] += v.y;
      o[mt2][4 * g + 2] += v.z; o[mt2][4 * g + 3] += v.w;
    }

  // ---- epilogue: finish l across kg halves, GeM inverse, packed stores ----
  {
    const float l = lsum + __shfl_xor(lsum, 32);
    const float inv = 1.0f / l;
    const int qg = q0 + wv * 32 + lm;
    const size_t base = ((size_t)qg * N_BATCH + nb) * E_DIM + h * H_DIM;
#pragma unroll
    for (int mt2 = 0; mt2 < 2; ++mt2)
#pragma unroll
      for (int g = 0; g < 4; ++g) {
        alignas(8) __hip_bfloat16 hb[4], lb[4];
#pragma unroll
        for (int i = 0; i < 4; ++i) {
          const int d = mt2 * 32 + 8 * g + 4 * kg + i;
          const int e = h * H_DIM + d;
          const float pooled = o[mt2][4 * g + i] * inv;
          const float val = __powf(fmaxf(pooled, EPS_F), 1.0f / pw[e]) - sw[e];
          split2(val, hb[i], lb[i]);
        }
        const int d0 = mt2 * 32 + 8 * g + 4 * kg;
        *(uint2*)(ohhi + base + d0) = *(const uint2*)hb;
        *(uint2*)(ohlo + base + d0) = *(const uint2*)lb;
      }
  }
}

// ---------------------------------------------------------------------------
// Kernel C: output projection via MFMA, hi/lo 3-pass.  (unchanged)
// ---------------------------------------------------------------------------
__global__ __launch_bounds__(256, 4) void out_proj_kernel(
    const __hip_bfloat16* __restrict__ xhi, const __hip_bfloat16* __restrict__ xlo,
    const __hip_bfloat16* __restrict__ whi, const __hip_bfloat16* __restrict__ wlo,
    const float* __restrict__ bias, float* __restrict__ out) {
  __shared__ __hip_bfloat16 Xh[128][40];
  __shared__ __hip_bfloat16 Xl[128][40];
  __shared__ __hip_bfloat16 Wh[64][40];
  __shared__ __hip_bfloat16 Wl[64][40];
  const int row0 = blockIdx.x * 128;
  const int col0 = blockIdx.y * 64;
  const int tid = threadIdx.x;
  const int lane = tid & 63;
  const int wv = tid >> 6;
  const int lidx = lane & 15;
  const int quad = lane >> 4;
  const int srow = tid >> 1;
  const int scol = (tid & 1) * 16;
  const int wrow = tid >> 2;
  const int wcol = (tid & 3) * 8;

  f32x4 acc[2][4];
#pragma unroll
  for (int rt = 0; rt < 2; ++rt)
#pragma unroll
    for (int ct = 0; ct < 4; ++ct) acc[rt][ct] = (f32x4){0.f, 0.f, 0.f, 0.f};

  const int ar0 = wv * 32 + lidx;

  for (int kt = 0; kt < 16; ++kt) {
    const int k0 = kt * 32;
    {
      const size_t xof = (size_t)(row0 + srow) * E_DIM + k0 + scol;
      *(uint4*)&Xh[srow][scol]     = ((const uint4*)(xhi + xof))[0];
      *(uint4*)&Xh[srow][scol + 8] = ((const uint4*)(xhi + xof))[1];
      *(uint4*)&Xl[srow][scol]     = ((const uint4*)(xlo + xof))[0];
      *(uint4*)&Xl[srow][scol + 8] = ((const uint4*)(xlo + xof))[1];
      const size_t wof = (size_t)(col0 + wrow) * E_DIM + k0 + wcol;
      *(uint4*)&Wh[wrow][wcol] = *(const uint4*)(whi + wof);
      *(uint4*)&Wl[wrow][wcol] = *(const uint4*)(wlo + wof);
    }
    __syncthreads();

    const bf16x8 ah0 = *(const bf16x8*)&Xh[ar0][quad * 8];
    const bf16x8 ah1 = *(const bf16x8*)&Xh[ar0 + 16][quad * 8];
    const bf16x8 al0 = *(const bf16x8*)&Xl[ar0][quad * 8];
    const bf16x8 al1 = *(const bf16x8*)&Xl[ar0 + 16][quad * 8];
#pragma unroll
    for (int ct = 0; ct < 4; ++ct) {
      const bf16x8 bh = *(const bf16x8*)&Wh[ct * 16 + lidx][quad * 8];
      const bf16x8 bl = *(const bf16x8*)&Wl[ct * 16 + lidx][quad * 8];
      acc[0][ct] = __builtin_amdgcn_mfma_f32_16x16x32_bf16(ah0, bh, acc[0][ct], 0, 0, 0);
      acc[0][ct] = __builtin_amdgcn_mfma_f32_16x16x32_bf16(al0, bh, acc[0][ct], 0, 0, 0);
      acc[0][ct] = __builtin_amdgcn_mfma_f32_16x16x32_bf16(ah0, bl, acc[0][ct], 0, 0, 0);
      acc[1][ct] = __builtin_amdgcn_mfma_f32_16x16x32_bf16(ah1, bh, acc[1][ct], 0, 0, 0);
      acc[1][ct] = __builtin_amdgcn_mfma_f32_16x16x32_bf16(al1, bh, acc[1][ct], 0, 0, 0);
      acc[1][ct] = __builtin_amdgcn_mfma_f32_16x16x32_bf16(ah1, bl, acc[1][ct], 0, 0, 0);
    }
    __syncthreads();
  }

  float bv[4];
#pragma unroll
  for (int ct = 0; ct < 4; ++ct) bv[ct] = bias[col0 + ct * 16 + lidx];
#pragma unroll
  for (int rt = 0; rt < 2; ++rt)
#pragma unroll
    for (int ct = 0; ct < 4; ++ct) {
      const int c = col0 + ct * 16 + lidx;
#pragma unroll
      for (int reg = 0; reg < 4; ++reg) {
        const int R = row0 + wv * 32 + rt * 16 + quad * 4 + reg;
        out[(size_t)R * E_DIM + c] = acc[rt][ct][reg] + bv[ct];
      }
    }
}

extern "C" void kernel_launch(void* const* d_in, const int* in_sizes, int n_in,
                              void* d_out, int out_size, void* d_ws, size_t ws_size,
                              hipStream_t stream) {
  const float* q_in = (const float*)d_in[0];
  const float* k_in = (const float*)d_in[1];
  const float* v_in = (const float*)d_in[2];
  const float* wio  = (const float*)d_in[3];
  const float* bio  = (const float*)d_in[4];
  const float* wo   = (const float*)d_in[5];
  const float* bo   = (const float*)d_in[6];
  const float* pw   = (const float*)d_in[7];
  const float* sw   = (const float*)d_in[8];

  // Workspace: qbuf,kbuf f16 (8 MiB ea); ubuf fp32 16 MiB (reused as
  // ohhi/ohlo bf16 8+8 after transp); uT f16 8 MiB; weight splits ~4 MiB.
  const size_t NE = (size_t)N_ROWS * E_DIM;
  _Float16* qbuf = (_Float16*)d_ws;
  _Float16* kbuf = qbuf + NE;
  float* ubuf = (float*)(kbuf + NE);
  _Float16* uT = (_Float16*)(ubuf + NE);
  __hip_bfloat16* wiohi = (__hip_bfloat16*)(uT + NE);
  __hip_bfloat16* wiolo = wiohi + 786432;
  __hip_bfloat16* wohi  = wiolo + 786432;
  __hip_bfloat16* wolo  = wohi + 262144;
  __hip_bfloat16* ohhi = (__hip_bfloat16*)ubuf;  // alias: ubuf dead after transp
  __hip_bfloat16* ohlo = ohhi + NE;

  wconv_kernel<<<dim3(1024), 256, 0, stream>>>(wio, wo, wiohi, wiolo, wohi, wolo);
  proj_qkv_kernel<<<dim3(64, 4, 3), 256, 0, stream>>>(q_in, k_in, v_in, wiohi,
                                                      bio, pw, sw, qbuf, kbuf, ubuf);
  transp_kernel<<<dim3(32, 8, 4), 256, 0, stream>>>(ubuf, uT);
  attn_kernel<<<dim3(32, 8, 4), 256, 0, stream>>>(qbuf, kbuf, uT, pw, sw,
                                                  ohhi, ohlo);
  out_proj_kernel<<<dim3(64, 8), 256, 0, stream>>>(ohhi, ohlo, wohi, wolo,
                                                   bo, (float*)d_out);
}

// Round 10
// 265.820 us; speedup vs baseline: 1.1545x; 1.0958x over previous
//
#include <hip/hip_runtime.h>
#include <hip/hip_bf16.h>

// Problem constants (L,N,E,H,D) = (2048,4,512,8,64)
#define E_DIM 512
#define N_BATCH 4
#define L_SEQ 2048
#define N_HEADS 8
#define H_DIM 64
#define N_ROWS (L_SEQ * N_BATCH) /* 8192 */
#define EPS_F 1e-6f
#define SC_Q 0.18033688f  /* 0.125 * log2(e): scores come out in log2 space */

typedef __attribute__((ext_vector_type(8))) short bf16x8;
typedef __attribute__((ext_vector_type(8))) _Float16 f16x8;
typedef __attribute__((ext_vector_type(4))) float f32x4;
typedef __attribute__((ext_vector_type(16))) float f32x16;

__device__ __forceinline__ void split2(float f, __hip_bfloat16& h, __hip_bfloat16& l) {
  h = __float2bfloat16(f);
  l = __float2bfloat16(f - __bfloat162float(h));
}

__device__ __forceinline__ unsigned int packf16(float a, float b) {
  union { _Float16 h[2]; unsigned int u; } c;
  c.h[0] = (_Float16)a;  // RN casts: unbiased (RTZ pkrtz would bias softmax weights)
  c.h[1] = (_Float16)b;
  return c.u;
}

// ---------------------------------------------------------------------------
// Kernel W: pre-split weights fp32 -> bf16 hi/lo.  (wiolo now unused by proj
// but kept for layout stability; wohi/wolo feed out_proj.)
// ---------------------------------------------------------------------------
__global__ __launch_bounds__(256) void wconv_kernel(
    const float* __restrict__ wio, const float* __restrict__ wo,
    __hip_bfloat16* __restrict__ wiohi, __hip_bfloat16* __restrict__ wiolo,
    __hip_bfloat16* __restrict__ wohi, __hip_bfloat16* __restrict__ wolo) {
  const int g = blockIdx.x * 256 + threadIdx.x;
  const float* src;
  __hip_bfloat16 *dh, *dl;
  int i;
  if (g < 196608) { src = wio; dh = wiohi; dl = wiolo; i = g * 4; }
  else            { src = wo;  dh = wohi;  dl = wolo;  i = (g - 196608) * 4; }
  const float4 f = *(const float4*)(src + i);
  alignas(8) __hip_bfloat16 h[4], l[4];
  split2(f.x, h[0], l[0]); split2(f.y, h[1], l[1]);
  split2(f.z, h[2], l[2]); split2(f.w, h[3], l[3]);
  *(uint2*)(dh + i) = *(const uint2*)h;
  *(uint2*)(dl + i) = *(const uint2*)l;
}

// ---------------------------------------------------------------------------
// Kernel A: packed QKV projection via MFMA, hi/lo 2-pass (hh + lh; the hl
// term x_hi*w_lo is dropped -- its ~6e-4 q/k/v error attenuates to ~2e-5
// through attention).  Q epilogue folds the 0.125*log2e softmax scale and
// stores fp16; K stores fp16; V stores u = max(v+sh,eps)^p directly as fp16
// (v10: rounding moved from transp to here -- final uT bit-identical, halves
// the u-roundtrip traffic).
// ---------------------------------------------------------------------------
__global__ __launch_bounds__(256, 3) void proj_qkv_kernel(
    const float* __restrict__ xq, const float* __restrict__ xk,
    const float* __restrict__ xv, const __hip_bfloat16* __restrict__ whi,
    const float* __restrict__ bias, const float* __restrict__ pw,
    const float* __restrict__ sw,
    _Float16* __restrict__ qbuf, _Float16* __restrict__ kbuf,
    _Float16* __restrict__ ubuf) {
  __shared__ __hip_bfloat16 Xh[128][40];
  __shared__ __hip_bfloat16 Xl[128][40];
  __shared__ __hip_bfloat16 Wh[128][40];
  const int z = blockIdx.z;
  const int row0 = blockIdx.x * 128;
  const int col0 = blockIdx.y * 128;
  const float* __restrict__ xsrc = (z == 0) ? xq : (z == 1) ? xk : xv;
  const int tid = threadIdx.x;
  const int lane = tid & 63;
  const int wv = tid >> 6;
  const int lidx = lane & 15;
  const int quad = lane >> 4;
  const int srow = tid >> 1;
  const int scol = (tid & 1) * 16;

  f32x4 acc[2][8];
#pragma unroll
  for (int rt = 0; rt < 2; ++rt)
#pragma unroll
    for (int ct = 0; ct < 8; ++ct) acc[rt][ct] = (f32x4){0.f, 0.f, 0.f, 0.f};

  const int ar0 = wv * 32 + lidx;

  for (int kt = 0; kt < 16; ++kt) {
    const int k0 = kt * 32;
    {
      const float* xp = xsrc + (size_t)(row0 + srow) * E_DIM + k0 + scol;
      float f[16];
      *(float4*)&f[0]  = ((const float4*)xp)[0];
      *(float4*)&f[4]  = ((const float4*)xp)[1];
      *(float4*)&f[8]  = ((const float4*)xp)[2];
      *(float4*)&f[12] = ((const float4*)xp)[3];
      alignas(16) __hip_bfloat16 hi[16], lo[16];
#pragma unroll
      for (int j = 0; j < 16; ++j) split2(f[j], hi[j], lo[j]);
      *(uint4*)&Xh[srow][scol]     = ((const uint4*)hi)[0];
      *(uint4*)&Xh[srow][scol + 8] = ((const uint4*)hi)[1];
      *(uint4*)&Xl[srow][scol]     = ((const uint4*)lo)[0];
      *(uint4*)&Xl[srow][scol + 8] = ((const uint4*)lo)[1];
    }
    {
      const size_t wof = (size_t)(z * E_DIM + col0 + srow) * E_DIM + k0 + scol;
      *(uint4*)&Wh[srow][scol]     = ((const uint4*)(whi + wof))[0];
      *(uint4*)&Wh[srow][scol + 8] = ((const uint4*)(whi + wof))[1];
    }
    __syncthreads();

    const bf16x8 ah0 = *(const bf16x8*)&Xh[ar0][quad * 8];
    const bf16x8 ah1 = *(const bf16x8*)&Xh[ar0 + 16][quad * 8];
    const bf16x8 al0 = *(const bf16x8*)&Xl[ar0][quad * 8];
    const bf16x8 al1 = *(const bf16x8*)&Xl[ar0 + 16][quad * 8];
#pragma unroll
    for (int ct = 0; ct < 8; ++ct) {
      const bf16x8 bh = *(const bf16x8*)&Wh[ct * 16 + lidx][quad * 8];
      acc[0][ct] = __builtin_amdgcn_mfma_f32_16x16x32_bf16(ah0, bh, acc[0][ct], 0, 0, 0);
      acc[0][ct] = __builtin_amdgcn_mfma_f32_16x16x32_bf16(al0, bh, acc[0][ct], 0, 0, 0);
      acc[1][ct] = __builtin_amdgcn_mfma_f32_16x16x32_bf16(ah1, bh, acc[1][ct], 0, 0, 0);
      acc[1][ct] = __builtin_amdgcn_mfma_f32_16x16x32_bf16(al1, bh, acc[1][ct], 0, 0, 0);
    }
    __syncthreads();
  }

  if (z < 2) {
    _Float16* __restrict__ dst = (z == 0) ? qbuf : kbuf;
    const float scale = (z == 0) ? SC_Q : 1.0f;
    float bv[8];
#pragma unroll
    for (int ct = 0; ct < 8; ++ct) bv[ct] = bias[z * E_DIM + col0 + ct * 16 + lidx];
#pragma unroll
    for (int rt = 0; rt < 2; ++rt)
#pragma unroll
      for (int ct = 0; ct < 8; ++ct) {
        const int e = col0 + ct * 16 + lidx;
        const int h = e >> 6, d = e & 63;
#pragma unroll
        for (int reg = 0; reg < 4; ++reg) {
          const int R = row0 + wv * 32 + rt * 16 + quad * 4 + reg;
          const int lpos = R >> 2, nb = R & 3;
          dst[(((size_t)nb * N_HEADS + h) * L_SEQ + lpos) * H_DIM + d] =
              (_Float16)((acc[rt][ct][reg] + bv[ct]) * scale);
        }
      }
  } else {
    float bv[8], pv[8], sv[8];
#pragma unroll
    for (int ct = 0; ct < 8; ++ct) {
      const int e = col0 + ct * 16 + lidx;
      bv[ct] = bias[2 * E_DIM + e]; pv[ct] = pw[e]; sv[ct] = sw[e];
    }
#pragma unroll
    for (int rt = 0; rt < 2; ++rt)
#pragma unroll
      for (int ct = 0; ct < 8; ++ct) {
        const int e = col0 + ct * 16 + lidx;
        const int h = e >> 6, d = e & 63;
#pragma unroll
        for (int reg = 0; reg < 4; ++reg) {
          const int R = row0 + wv * 32 + rt * 16 + quad * 4 + reg;
          const int lpos = R >> 2, nb = R & 3;
          const float y = acc[rt][ct][reg] + bv[ct];
          const float vp = fmaxf(y + sv[ct], EPS_F);
          ubuf[(((size_t)nb * N_HEADS + h) * L_SEQ + lpos) * H_DIM + d] =
              (_Float16)__powf(vp, pv[ct]);
        }
      }
  }
}

// ---------------------------------------------------------------------------
// Kernel T: transpose u (n,h,l,d) fp16 -> u^T (n,h,d,l) fp16.  (v10: input
// is already fp16 -- pure data movement, half the prior read traffic.)
// ---------------------------------------------------------------------------
__global__ __launch_bounds__(256) void transp_kernel(
    const _Float16* __restrict__ u, _Float16* __restrict__ uT) {
  __shared__ _Float16 T[64][72];
  const int lt = blockIdx.x, h = blockIdx.y, nb = blockIdx.z;
  const int tid = threadIdx.x;
  const int r = tid >> 2;
  const int cb = (tid & 3) * 16;
  const size_t srcbase = ((size_t)nb * N_HEADS + h) * L_SEQ + lt * 64;
  {
    const _Float16* p = u + (srcbase + r) * H_DIM + cb;
    *(uint4*)&T[r][cb + 0] = ((const uint4*)p)[0];
    *(uint4*)&T[r][cb + 8] = ((const uint4*)p)[1];
  }
  __syncthreads();
  alignas(16) _Float16 hv[16];
#pragma unroll
  for (int j = 0; j < 16; ++j) hv[j] = T[cb + j][r];
  const size_t dst = (((size_t)nb * N_HEADS + h) * H_DIM + r) * L_SEQ + lt * 64 + cb;
  *(uint4*)(uT + dst)     = ((const uint4*)hv)[0];
  *(uint4*)(uT + dst + 8) = ((const uint4*)hv)[1];
}

// ---------------------------------------------------------------------------
// Kernel B: fp16 MFMA flash attention, S^T orientation (A=K, B=Q) so P lives
// in registers in B-operand layout (q = lane&31): one shfl_xor(32) exchange
// replaces the LDS P round-trip.  O^T = U^T @ P^T; l = per-lane scalar sum.
//
// v10 = v6 (proven 98.4us: 256-row window, two-barrier, Ks0/Us0+Ks1/Us1,
// 2 blocks/CU, VGPR 124 no-spill) + T1 XCD remap ONLY.  v6's stall is the
// staging-load window (all pipes <40%); FETCH 70MB vs ~25MB unique = K/U
// panels re-fetched ~4x from L3/HBM (~600-900cy).  Remap: flatten grid to
// 512, each XCD's 64 blocks cover 4 (h,nb) heads x 16 q-tiles -> per-XCD
// working set ~3MB fits its 4MB L2 -> staging loads become ~200cy L2 hits.
// Decode f=(t*16+qt)*8+xcd is bijective (mixed-radix) -- pure relabeling,
// correctness-neutral.  (v4/v5's races were bundled with the register
// prefetch, which remains dead; remap is math-checkable.)
// 64-q direction closed: allocator spills it at ANY launch_bounds (v7/v8/v9).
// Grid 512 x 256 thr.
// ---------------------------------------------------------------------------
__global__ __launch_bounds__(256, 2) void attn_kernel(
    const _Float16* __restrict__ qbuf, const _Float16* __restrict__ kbuf,
    const _Float16* __restrict__ uT, const float* __restrict__ pw,
    const float* __restrict__ sw, __hip_bfloat16* __restrict__ ohhi,
    __hip_bfloat16* __restrict__ ohlo) {
  __shared__ union {
    struct { _Float16 Ks0[128][72]; _Float16 Us0[64][136];
             _Float16 Ks1[128][72]; _Float16 Us1[64][136]; } st;
    struct { float A[2][64][64]; float lA[2][2][64]; } red;
  } sm;
  // XCD-clustered decode: f -> xcd = f&7 (dispatch round-robin); XCD x owns
  // heads [4x,4x+4) x all 16 q-tiles.  Bijective: f = ((hidx&3)*16+qt)*8+xcd.
  const int f = blockIdx.x;              // 0..511
  const int xcd = f & 7;
  const int j = f >> 3;                  // 0..63
  const int qt = j & 15;
  const int hidx = xcd * 4 + (j >> 4);   // 0..31
  const int h = hidx & 7, nb = hidx >> 3;
  const int q0 = qt * 128;
  const int tid = threadIdx.x;
  const int lane = tid & 63;
  const int w = tid >> 6;           // wave 0..3
  const int wv = w & 1;             // q-half of the block tile
  const int sg = w >> 1;            // s-group 0..1
  const int lm = lane & 31;
  const int kg = lane >> 5;         // k-group within MFMA operands
  const int srow = tid >> 1;        // K staging row 0..127
  const int scb = (tid & 1) * 32;   // K staging col base (fp16 units)
  const int urow = tid >> 2;        // U staging row (d) 0..63
  const int ucb = (tid & 3) * 32;   // U staging col base (s units)
  const size_t headbase = ((size_t)nb * N_HEADS + h) * L_SEQ;
  const size_t dbase = ((size_t)nb * N_HEADS + h) * H_DIM;

  // hoist Q B-frags straight from global (no Q LDS): q(nt) = q0+wv*64+nt*32+lm
  f16x8 bq[2][4];
#pragma unroll
  for (int nt = 0; nt < 2; ++nt)
#pragma unroll
    for (int kc = 0; kc < 4; ++kc)
      bq[nt][kc] = *(const f16x8*)(qbuf +
          (headbase + q0 + wv * 64 + nt * 32 + lm) * H_DIM + kc * 16 + kg * 8);

  f32x16 o[2][2];  // [q-half nt][d-half mt2]
  o[0][0] = (f32x16)(0.f); o[0][1] = (f32x16)(0.f);
  o[1][0] = (f32x16)(0.f); o[1][1] = (f32x16)(0.f);
  float lsum[2] = {0.f, 0.f};

  // compute one 64-row s-slice from a staged half-tile (v3's body verbatim)
  auto do_half = [&](const _Float16 (&Ks)[128][72], const _Float16 (&Us)[64][136]) {
    const int sr = sg * 64;  // this wave's s-rows within the staged 128

    // ---- S^T: sc[nt][mt], C-layout row = s_local, col = q (lane&31) ----
    f32x16 sc[2][2];
    sc[0][0] = (f32x16)(0.f); sc[0][1] = (f32x16)(0.f);
    sc[1][0] = (f32x16)(0.f); sc[1][1] = (f32x16)(0.f);
#pragma unroll
    for (int kc = 0; kc < 4; ++kc) {
      const f16x8 ak0 = *(const f16x8*)&Ks[sr + lm][kc * 16 + kg * 8];
      const f16x8 ak1 = *(const f16x8*)&Ks[sr + 32 + lm][kc * 16 + kg * 8];
      sc[0][0] = __builtin_amdgcn_mfma_f32_32x32x16_f16(ak0, bq[0][kc], sc[0][0], 0, 0, 0);
      sc[0][1] = __builtin_amdgcn_mfma_f32_32x32x16_f16(ak1, bq[0][kc], sc[0][1], 0, 0, 0);
      sc[1][0] = __builtin_amdgcn_mfma_f32_32x32x16_f16(ak0, bq[1][kc], sc[1][0], 0, 0, 0);
      sc[1][1] = __builtin_amdgcn_mfma_f32_32x32x16_f16(ak1, bq[1][kc], sc[1][1], 0, 0, 0);
    }

    // ---- p = exp2(score); pack fp16 pairs; per-lane l partial sum ----
    unsigned int P2[2][2][4][2];
#pragma unroll
    for (int nt = 0; nt < 2; ++nt)
#pragma unroll
      for (int mt = 0; mt < 2; ++mt)
#pragma unroll
        for (int g = 0; g < 4; ++g) {
          const float p0 = __builtin_amdgcn_exp2f(sc[nt][mt][4 * g + 0]);
          const float p1 = __builtin_amdgcn_exp2f(sc[nt][mt][4 * g + 1]);
          const float p2 = __builtin_amdgcn_exp2f(sc[nt][mt][4 * g + 2]);
          const float p3 = __builtin_amdgcn_exp2f(sc[nt][mt][4 * g + 3]);
          lsum[nt] += (p0 + p1) + (p2 + p3);
          P2[nt][mt][g][0] = packf16(p0, p1);
          P2[nt][mt][g][1] = packf16(p2, p3);
        }

    // ---- PV: O^T += U^T @ P^T; P B-frags via xor-32 exchange ----
#pragma unroll
    for (int kc = 0; kc < 4; ++kc) {
      const int mt = kc >> 1;
      const f16x8 au0 = *(const f16x8*)&Us[lm][sr + kc * 16 + kg * 8];
      const f16x8 au1 = *(const f16x8*)&Us[32 + lm][sr + kc * 16 + kg * 8];
#pragma unroll
      for (int nt = 0; nt < 2; ++nt) {
        const int gx = (2 * kc) & 3, gy = (2 * kc + 1) & 3;
        const unsigned int x0 = P2[nt][mt][gx][0], x1 = P2[nt][mt][gx][1];
        const unsigned int y0 = P2[nt][mt][gy][0], y1 = P2[nt][mt][gy][1];
        const unsigned int sA = kg ? x0 : y0, sB = kg ? x1 : y1;
        const unsigned int rA = (unsigned int)__shfl_xor((int)sA, 32);
        const unsigned int rB = (unsigned int)__shfl_xor((int)sB, 32);
        union { unsigned int u[4]; f16x8 v; } bp;
        bp.u[0] = kg ? rA : x0;  // j0..3: s = kc*16+kg*8+0..3
        bp.u[1] = kg ? rB : x1;
        bp.u[2] = kg ? y0 : rA;  // j4..7: s = kc*16+kg*8+4..7
        bp.u[3] = kg ? y1 : rB;
        o[nt][0] = __builtin_amdgcn_mfma_f32_32x32x16_f16(au0, bp.v, o[nt][0], 0, 0, 0);
        o[nt][1] = __builtin_amdgcn_mfma_f32_32x32x16_f16(au1, bp.v, o[nt][1], 0, 0, 0);
      }
    }
  };

  for (int it = 0; it < 8; ++it) {
    const int s0 = it * 256;
    __syncthreads();  // B1: prior window's frag reads complete
    {
      const _Float16* kp = kbuf + (headbase + s0 + srow) * H_DIM + scb;
      *(uint4*)&sm.st.Ks0[srow][scb + 0]  = ((const uint4*)kp)[0];
      *(uint4*)&sm.st.Ks0[srow][scb + 8]  = ((const uint4*)kp)[1];
      *(uint4*)&sm.st.Ks0[srow][scb + 16] = ((const uint4*)kp)[2];
      *(uint4*)&sm.st.Ks0[srow][scb + 24] = ((const uint4*)kp)[3];
      const _Float16* kq = kbuf + (headbase + s0 + 128 + srow) * H_DIM + scb;
      *(uint4*)&sm.st.Ks1[srow][scb + 0]  = ((const uint4*)kq)[0];
      *(uint4*)&sm.st.Ks1[srow][scb + 8]  = ((const uint4*)kq)[1];
      *(uint4*)&sm.st.Ks1[srow][scb + 16] = ((const uint4*)kq)[2];
      *(uint4*)&sm.st.Ks1[srow][scb + 24] = ((const uint4*)kq)[3];
      const _Float16* up = uT + (dbase + urow) * L_SEQ + s0 + ucb;
      *(uint4*)&sm.st.Us0[urow][ucb + 0]  = ((const uint4*)up)[0];
      *(uint4*)&sm.st.Us0[urow][ucb + 8]  = ((const uint4*)up)[1];
      *(uint4*)&sm.st.Us0[urow][ucb + 16] = ((const uint4*)up)[2];
      *(uint4*)&sm.st.Us0[urow][ucb + 24] = ((const uint4*)up)[3];
      const _Float16* uq = up + 128;
      *(uint4*)&sm.st.Us1[urow][ucb + 0]  = ((const uint4*)uq)[0];
      *(uint4*)&sm.st.Us1[urow][ucb + 8]  = ((const uint4*)uq)[1];
      *(uint4*)&sm.st.Us1[urow][ucb + 16] = ((const uint4*)uq)[2];
      *(uint4*)&sm.st.Us1[urow][ucb + 24] = ((const uint4*)uq)[3];
    }
    __syncthreads();  // B2: staged 256-row tile visible to all waves

    do_half(sm.st.Ks0, sm.st.Us0);
    do_half(sm.st.Ks1, sm.st.Us1);
  }

  // ---- cross-s-group reduction in LDS: sg1 publishes (o, lsum), sg0
  //      accumulates.  XOR-swizzled float4 slots keep accesses at the
  //      8-dwords/bank wave64 minimum (conflict-free).  ----
  float* redA = &sm.red.A[0][0][0];
  float* lrA = &sm.red.lA[0][0][0];

  __syncthreads();  // loop's trailing frag reads complete before LDS reuse
  if (sg == 1) {
#pragma unroll
    for (int nt = 0; nt < 2; ++nt) {
      lrA[(wv * 2 + nt) * 64 + lane] = lsum[nt];
#pragma unroll
      for (int mt2 = 0; mt2 < 2; ++mt2)
#pragma unroll
        for (int g = 0; g < 4; ++g) {
          const int i4 = ((nt * 2 + mt2) * 4 + g) ^ (lane & 7);
          float4 v = {o[nt][mt2][4 * g + 0], o[nt][mt2][4 * g + 1],
                      o[nt][mt2][4 * g + 2], o[nt][mt2][4 * g + 3]};
          *(float4*)(redA + ((size_t)(wv * 64 + lane)) * 64 + i4 * 4) = v;
        }
    }
  }
  __syncthreads();
  if (sg == 1) return;  // sg0 past this point; no further barriers
#pragma unroll
  for (int nt = 0; nt < 2; ++nt) {
    lsum[nt] += lrA[(wv * 2 + nt) * 64 + lane];
#pragma unroll
    for (int mt2 = 0; mt2 < 2; ++mt2)
#pragma unroll
      for (int g = 0; g < 4; ++g) {
        const int i4 = ((nt * 2 + mt2) * 4 + g) ^ (lane & 7);
        const float4 v =
            *(const float4*)(redA + ((size_t)(wv * 64 + lane)) * 64 + i4 * 4);
        o[nt][mt2][4 * g + 0] += v.x; o[nt][mt2][4 * g + 1] += v.y;
        o[nt][mt2][4 * g + 2] += v.z; o[nt][mt2][4 * g + 3] += v.w;
      }
  }

  // ---- epilogue: finish l across kg halves, GeM inverse, packed stores ----
#pragma unroll
  for (int nt = 0; nt < 2; ++nt) {
    const float l = lsum[nt] + __shfl_xor(lsum[nt], 32);
    const float inv = 1.0f / l;
    const int qg = q0 + wv * 64 + nt * 32 + lm;
    const size_t base = ((size_t)qg * N_BATCH + nb) * E_DIM + h * H_DIM;
#pragma unroll
    for (int mt2 = 0; mt2 < 2; ++mt2)
#pragma unroll
      for (int g = 0; g < 4; ++g) {
        alignas(8) __hip_bfloat16 hb[4], lb[4];
#pragma unroll
        for (int i = 0; i < 4; ++i) {
          const int d = mt2 * 32 + 8 * g + 4 * kg + i;
          const int e = h * H_DIM + d;
          const float pooled = o[nt][mt2][4 * g + i] * inv;
          const float val = __powf(fmaxf(pooled, EPS_F), 1.0f / pw[e]) - sw[e];
          split2(val, hb[i], lb[i]);
        }
        const int d0 = mt2 * 32 + 8 * g + 4 * kg;
        *(uint2*)(ohhi + base + d0) = *(const uint2*)hb;
        *(uint2*)(ohlo + base + d0) = *(const uint2*)lb;
      }
  }
}

// ---------------------------------------------------------------------------
// Kernel C: output projection via MFMA, hi/lo 3-pass.  (unchanged)
// ---------------------------------------------------------------------------
__global__ __launch_bounds__(256, 4) void out_proj_kernel(
    const __hip_bfloat16* __restrict__ xhi, const __hip_bfloat16* __restrict__ xlo,
    const __hip_bfloat16* __restrict__ whi, const __hip_bfloat16* __restrict__ wlo,
    const float* __restrict__ bias, float* __restrict__ out) {
  __shared__ __hip_bfloat16 Xh[128][40];
  __shared__ __hip_bfloat16 Xl[128][40];
  __shared__ __hip_bfloat16 Wh[64][40];
  __shared__ __hip_bfloat16 Wl[64][40];
  const int row0 = blockIdx.x * 128;
  const int col0 = blockIdx.y * 64;
  const int tid = threadIdx.x;
  const int lane = tid & 63;
  const int wv = tid >> 6;
  const int lidx = lane & 15;
  const int quad = lane >> 4;
  const int srow = tid >> 1;
  const int scol = (tid & 1) * 16;
  const int wrow = tid >> 2;
  const int wcol = (tid & 3) * 8;

  f32x4 acc[2][4];
#pragma unroll
  for (int rt = 0; rt < 2; ++rt)
#pragma unroll
    for (int ct = 0; ct < 4; ++ct) acc[rt][ct] = (f32x4){0.f, 0.f, 0.f, 0.f};

  const int ar0 = wv * 32 + lidx;

  for (int kt = 0; kt < 16; ++kt) {
    const int k0 = kt * 32;
    {
      const size_t xof = (size_t)(row0 + srow) * E_DIM + k0 + scol;
      *(uint4*)&Xh[srow][scol]     = ((const uint4*)(xhi + xof))[0];
      *(uint4*)&Xh[srow][scol + 8] = ((const uint4*)(xhi + xof))[1];
      *(uint4*)&Xl[srow][scol]     = ((const uint4*)(xlo + xof))[0];
      *(uint4*)&Xl[srow][scol + 8] = ((const uint4*)(xlo + xof))[1];
      const size_t wof = (size_t)(col0 + wrow) * E_DIM + k0 + wcol;
      *(uint4*)&Wh[wrow][wcol] = *(const uint4*)(whi + wof);
      *(uint4*)&Wl[wrow][wcol] = *(const uint4*)(wlo + wof);
    }
    __syncthreads();

    const bf16x8 ah0 = *(const bf16x8*)&Xh[ar0][quad * 8];
    const bf16x8 ah1 = *(const bf16x8*)&Xh[ar0 + 16][quad * 8];
    const bf16x8 al0 = *(const bf16x8*)&Xl[ar0][quad * 8];
    const bf16x8 al1 = *(const bf16x8*)&Xl[ar0 + 16][quad * 8];
#pragma unroll
    for (int ct = 0; ct < 4; ++ct) {
      const bf16x8 bh = *(const bf16x8*)&Wh[ct * 16 + lidx][quad * 8];
      const bf16x8 bl = *(const bf16x8*)&Wl[ct * 16 + lidx][quad * 8];
      acc[0][ct] = __builtin_amdgcn_mfma_f32_16x16x32_bf16(ah0, bh, acc[0][ct], 0, 0, 0);
      acc[0][ct] = __builtin_amdgcn_mfma_f32_16x16x32_bf16(al0, bh, acc[0][ct], 0, 0, 0);
      acc[0][ct] = __builtin_amdgcn_mfma_f32_16x16x32_bf16(ah0, bl, acc[0][ct], 0, 0, 0);
      acc[1][ct] = __builtin_amdgcn_mfma_f32_16x16x32_bf16(ah1, bh, acc[1][ct], 0, 0, 0);
      acc[1][ct] = __builtin_amdgcn_mfma_f32_16x16x32_bf16(al1, bh, acc[1][ct], 0, 0, 0);
      acc[1][ct] = __builtin_amdgcn_mfma_f32_16x16x32_bf16(ah1, bl, acc[1][ct], 0, 0, 0);
    }
    __syncthreads();
  }

  float bv[4];
#pragma unroll
  for (int ct = 0; ct < 4; ++ct) bv[ct] = bias[col0 + ct * 16 + lidx];
#pragma unroll
  for (int rt = 0; rt < 2; ++rt)
#pragma unroll
    for (int ct = 0; ct < 4; ++ct) {
      const int c = col0 + ct * 16 + lidx;
#pragma unroll
      for (int reg = 0; reg < 4; ++reg) {
        const int R = row0 + wv * 32 + rt * 16 + quad * 4 + reg;
        out[(size_t)R * E_DIM + c] = acc[rt][ct][reg] + bv[ct];
      }
    }
}

extern "C" void kernel_launch(void* const* d_in, const int* in_sizes, int n_in,
                              void* d_out, int out_size, void* d_ws, size_t ws_size,
                              hipStream_t stream) {
  const float* q_in = (const float*)d_in[0];
  const float* k_in = (const float*)d_in[1];
  const float* v_in = (const float*)d_in[2];
  const float* wio  = (const float*)d_in[3];
  const float* bio  = (const float*)d_in[4];
  const float* wo   = (const float*)d_in[5];
  const float* bo   = (const float*)d_in[6];
  const float* pw   = (const float*)d_in[7];
  const float* sw   = (const float*)d_in[8];

  // Workspace layout unchanged (ubuf region now holds fp16 u in its first
  // half; ohhi/ohlo alias it after transp consumes u).
  const size_t NE = (size_t)N_ROWS * E_DIM;
  _Float16* qbuf = (_Float16*)d_ws;
  _Float16* kbuf = qbuf + NE;
  float* ubuf = (float*)(kbuf + NE);
  _Float16* uT = (_Float16*)(ubuf + NE);
  __hip_bfloat16* wiohi = (__hip_bfloat16*)(uT + NE);
  __hip_bfloat16* wiolo = wiohi + 786432;
  __hip_bfloat16* wohi  = wiolo + 786432;
  __hip_bfloat16* wolo  = wohi + 262144;
  __hip_bfloat16* ohhi = (__hip_bfloat16*)ubuf;  // alias: ubuf dead after transp
  __hip_bfloat16* ohlo = ohhi + NE;

  wconv_kernel<<<dim3(1024), 256, 0, stream>>>(wio, wo, wiohi, wiolo, wohi, wolo);
  proj_qkv_kernel<<<dim3(64, 4, 3), 256, 0, stream>>>(q_in, k_in, v_in, wiohi,
                                                      bio, pw, sw, qbuf, kbuf,
                                                      (_Float16*)ubuf);
  transp_kernel<<<dim3(32, 8, 4), 256, 0, stream>>>((const _Float16*)ubuf, uT);
  attn_kernel<<<dim3(512), 256, 0, stream>>>(qbuf, kbuf, uT, pw, sw,
                                             ohhi, ohlo);
  out_proj_kernel<<<dim3(64, 8), 256, 0, stream>>>(ohhi, ohlo, wohi, wolo,
                                                   bo, (float*)d_out);
}

// Round 11
// 260.263 us; speedup vs baseline: 1.1792x; 1.0214x over previous
//
#include <hip/hip_runtime.h>
#include <hip/hip_bf16.h>

// Problem constants (L,N,E,H,D) = (2048,4,512,8,64)
#define E_DIM 512
#define N_BATCH 4
#define L_SEQ 2048
#define N_HEADS 8
#define H_DIM 64
#define N_ROWS (L_SEQ * N_BATCH) /* 8192 */
#define EPS_F 1e-6f
#define SC_Q 0.18033688f  /* 0.125 * log2(e): scores come out in log2 space */

typedef __attribute__((ext_vector_type(8))) short bf16x8;
typedef __attribute__((ext_vector_type(8))) _Float16 f16x8;
typedef __attribute__((ext_vector_type(4))) float f32x4;
typedef __attribute__((ext_vector_type(16))) float f32x16;

__device__ __forceinline__ void split2(float f, __hip_bfloat16& h, __hip_bfloat16& l) {
  h = __float2bfloat16(f);
  l = __float2bfloat16(f - __bfloat162float(h));
}

__device__ __forceinline__ unsigned int packf16(float a, float b) {
  union { _Float16 h[2]; unsigned int u; } c;
  c.h[0] = (_Float16)a;  // RN casts: unbiased (RTZ pkrtz would bias softmax weights)
  c.h[1] = (_Float16)b;
  return c.u;
}

// ---------------------------------------------------------------------------
// Kernel W: pre-split weights fp32 -> bf16 hi/lo.  (wiolo now unused by proj
// but kept for layout stability; wohi/wolo feed out_proj.)
// ---------------------------------------------------------------------------
__global__ __launch_bounds__(256) void wconv_kernel(
    const float* __restrict__ wio, const float* __restrict__ wo,
    __hip_bfloat16* __restrict__ wiohi, __hip_bfloat16* __restrict__ wiolo,
    __hip_bfloat16* __restrict__ wohi, __hip_bfloat16* __restrict__ wolo) {
  const int g = blockIdx.x * 256 + threadIdx.x;
  const float* src;
  __hip_bfloat16 *dh, *dl;
  int i;
  if (g < 196608) { src = wio; dh = wiohi; dl = wiolo; i = g * 4; }
  else            { src = wo;  dh = wohi;  dl = wolo;  i = (g - 196608) * 4; }
  const float4 f = *(const float4*)(src + i);
  alignas(8) __hip_bfloat16 h[4], l[4];
  split2(f.x, h[0], l[0]); split2(f.y, h[1], l[1]);
  split2(f.z, h[2], l[2]); split2(f.w, h[3], l[3]);
  *(uint2*)(dh + i) = *(const uint2*)h;
  *(uint2*)(dl + i) = *(const uint2*)l;
}

// ---------------------------------------------------------------------------
// Kernel A: packed QKV projection via MFMA, hi/lo 2-pass (hh + lh; the hl
// term x_hi*w_lo is dropped -- its ~6e-4 q/k/v error attenuates to ~2e-5
// through attention).  Q epilogue folds the 0.125*log2e softmax scale and
// stores fp16; K stores fp16; V stores u = max(v+sh,eps)^p directly as fp16.
// ---------------------------------------------------------------------------
__global__ __launch_bounds__(256, 3) void proj_qkv_kernel(
    const float* __restrict__ xq, const float* __restrict__ xk,
    const float* __restrict__ xv, const __hip_bfloat16* __restrict__ whi,
    const float* __restrict__ bias, const float* __restrict__ pw,
    const float* __restrict__ sw,
    _Float16* __restrict__ qbuf, _Float16* __restrict__ kbuf,
    _Float16* __restrict__ ubuf) {
  __shared__ __hip_bfloat16 Xh[128][40];
  __shared__ __hip_bfloat16 Xl[128][40];
  __shared__ __hip_bfloat16 Wh[128][40];
  const int z = blockIdx.z;
  const int row0 = blockIdx.x * 128;
  const int col0 = blockIdx.y * 128;
  const float* __restrict__ xsrc = (z == 0) ? xq : (z == 1) ? xk : xv;
  const int tid = threadIdx.x;
  const int lane = tid & 63;
  const int wv = tid >> 6;
  const int lidx = lane & 15;
  const int quad = lane >> 4;
  const int srow = tid >> 1;
  const int scol = (tid & 1) * 16;

  f32x4 acc[2][8];
#pragma unroll
  for (int rt = 0; rt < 2; ++rt)
#pragma unroll
    for (int ct = 0; ct < 8; ++ct) acc[rt][ct] = (f32x4){0.f, 0.f, 0.f, 0.f};

  const int ar0 = wv * 32 + lidx;

  for (int kt = 0; kt < 16; ++kt) {
    const int k0 = kt * 32;
    {
      const float* xp = xsrc + (size_t)(row0 + srow) * E_DIM + k0 + scol;
      float f[16];
      *(float4*)&f[0]  = ((const float4*)xp)[0];
      *(float4*)&f[4]  = ((const float4*)xp)[1];
      *(float4*)&f[8]  = ((const float4*)xp)[2];
      *(float4*)&f[12] = ((const float4*)xp)[3];
      alignas(16) __hip_bfloat16 hi[16], lo[16];
#pragma unroll
      for (int j = 0; j < 16; ++j) split2(f[j], hi[j], lo[j]);
      *(uint4*)&Xh[srow][scol]     = ((const uint4*)hi)[0];
      *(uint4*)&Xh[srow][scol + 8] = ((const uint4*)hi)[1];
      *(uint4*)&Xl[srow][scol]     = ((const uint4*)lo)[0];
      *(uint4*)&Xl[srow][scol + 8] = ((const uint4*)lo)[1];
    }
    {
      const size_t wof = (size_t)(z * E_DIM + col0 + srow) * E_DIM + k0 + scol;
      *(uint4*)&Wh[srow][scol]     = ((const uint4*)(whi + wof))[0];
      *(uint4*)&Wh[srow][scol + 8] = ((const uint4*)(whi + wof))[1];
    }
    __syncthreads();

    const bf16x8 ah0 = *(const bf16x8*)&Xh[ar0][quad * 8];
    const bf16x8 ah1 = *(const bf16x8*)&Xh[ar0 + 16][quad * 8];
    const bf16x8 al0 = *(const bf16x8*)&Xl[ar0][quad * 8];
    const bf16x8 al1 = *(const bf16x8*)&Xl[ar0 + 16][quad * 8];
#pragma unroll
    for (int ct = 0; ct < 8; ++ct) {
      const bf16x8 bh = *(const bf16x8*)&Wh[ct * 16 + lidx][quad * 8];
      acc[0][ct] = __builtin_amdgcn_mfma_f32_16x16x32_bf16(ah0, bh, acc[0][ct], 0, 0, 0);
      acc[0][ct] = __builtin_amdgcn_mfma_f32_16x16x32_bf16(al0, bh, acc[0][ct], 0, 0, 0);
      acc[1][ct] = __builtin_amdgcn_mfma_f32_16x16x32_bf16(ah1, bh, acc[1][ct], 0, 0, 0);
      acc[1][ct] = __builtin_amdgcn_mfma_f32_16x16x32_bf16(al1, bh, acc[1][ct], 0, 0, 0);
    }
    __syncthreads();
  }

  if (z < 2) {
    _Float16* __restrict__ dst = (z == 0) ? qbuf : kbuf;
    const float scale = (z == 0) ? SC_Q : 1.0f;
    float bv[8];
#pragma unroll
    for (int ct = 0; ct < 8; ++ct) bv[ct] = bias[z * E_DIM + col0 + ct * 16 + lidx];
#pragma unroll
    for (int rt = 0; rt < 2; ++rt)
#pragma unroll
      for (int ct = 0; ct < 8; ++ct) {
        const int e = col0 + ct * 16 + lidx;
        const int h = e >> 6, d = e & 63;
#pragma unroll
        for (int reg = 0; reg < 4; ++reg) {
          const int R = row0 + wv * 32 + rt * 16 + quad * 4 + reg;
          const int lpos = R >> 2, nb = R & 3;
          dst[(((size_t)nb * N_HEADS + h) * L_SEQ + lpos) * H_DIM + d] =
              (_Float16)((acc[rt][ct][reg] + bv[ct]) * scale);
        }
      }
  } else {
    float bv[8], pv[8], sv[8];
#pragma unroll
    for (int ct = 0; ct < 8; ++ct) {
      const int e = col0 + ct * 16 + lidx;
      bv[ct] = bias[2 * E_DIM + e]; pv[ct] = pw[e]; sv[ct] = sw[e];
    }
#pragma unroll
    for (int rt = 0; rt < 2; ++rt)
#pragma unroll
      for (int ct = 0; ct < 8; ++ct) {
        const int e = col0 + ct * 16 + lidx;
        const int h = e >> 6, d = e & 63;
#pragma unroll
        for (int reg = 0; reg < 4; ++reg) {
          const int R = row0 + wv * 32 + rt * 16 + quad * 4 + reg;
          const int lpos = R >> 2, nb = R & 3;
          const float y = acc[rt][ct][reg] + bv[ct];
          const float vp = fmaxf(y + sv[ct], EPS_F);
          ubuf[(((size_t)nb * N_HEADS + h) * L_SEQ + lpos) * H_DIM + d] =
              (_Float16)__powf(vp, pv[ct]);
        }
      }
  }
}

// ---------------------------------------------------------------------------
// Kernel T: transpose u (n,h,l,d) fp16 -> u^T (n,h,d,l) fp16.
// ---------------------------------------------------------------------------
__global__ __launch_bounds__(256) void transp_kernel(
    const _Float16* __restrict__ u, _Float16* __restrict__ uT) {
  __shared__ _Float16 T[64][72];
  const int lt = blockIdx.x, h = blockIdx.y, nb = blockIdx.z;
  const int tid = threadIdx.x;
  const int r = tid >> 2;
  const int cb = (tid & 3) * 16;
  const size_t srcbase = ((size_t)nb * N_HEADS + h) * L_SEQ + lt * 64;
  {
    const _Float16* p = u + (srcbase + r) * H_DIM + cb;
    *(uint4*)&T[r][cb + 0] = ((const uint4*)p)[0];
    *(uint4*)&T[r][cb + 8] = ((const uint4*)p)[1];
  }
  __syncthreads();
  alignas(16) _Float16 hv[16];
#pragma unroll
  for (int j = 0; j < 16; ++j) hv[j] = T[cb + j][r];
  const size_t dst = (((size_t)nb * N_HEADS + h) * H_DIM + r) * L_SEQ + lt * 64 + cb;
  *(uint4*)(uT + dst)     = ((const uint4*)hv)[0];
  *(uint4*)(uT + dst + 8) = ((const uint4*)hv)[1];
}

// ---------------------------------------------------------------------------
// Kernel B: fp16 MFMA flash attention, S^T orientation (A=K, B=Q) so P lives
// in registers in B-operand layout (q = lane&31).  O^T = U^T @ P^T.
//
// v11 = v10 (265.8us total; attn 97us, FETCH 12.8MB after XCD remap proved
// memory is NOT the bottleneck: L2-hit loads, time unchanged) + compute-path
// thinning.  Counters: MfmaUtil 14.5 + VALUBusy 36.6 => ~49% of cycles
// neither pipe issues at 2 waves/SIMD -- dependency stalls.  Worst chain:
// PV's per-(kc,nt) exchange = 2x shfl_xor(32) (ds_permute, ~60cy LDS-pipe
// latency) + 6 cndmask feeding MFMA.
//   (a) T12 primitive: v_permlane32_swap_b32 a,b swaps a[32..63]<->b[0..31].
//       Element-wise identity (verified): a' == bp.u[0], b' == bp.u[2] of
//       the old network.  2 swaps replace 2 ds_permutes + 6 selects; pure
//       VALU, no LDS pipe, bit-identical result.  (m255: permlane 1.20x
//       vs ds_bpermute on MI355X.)
//   (b) T5: s_setprio(1) around the MFMA clusters (2 independent blocks/CU
//       at different phases -> scheduler can favor the computing wave).
//       Hint only; cannot affect values.
// Everything else (grid, barriers, staging, reduction, epilogue) = v10.
// Grid 512 x 256 thr.
// ---------------------------------------------------------------------------
__global__ __launch_bounds__(256, 2) void attn_kernel(
    const _Float16* __restrict__ qbuf, const _Float16* __restrict__ kbuf,
    const _Float16* __restrict__ uT, const float* __restrict__ pw,
    const float* __restrict__ sw, __hip_bfloat16* __restrict__ ohhi,
    __hip_bfloat16* __restrict__ ohlo) {
  __shared__ union {
    struct { _Float16 Ks0[128][72]; _Float16 Us0[64][136];
             _Float16 Ks1[128][72]; _Float16 Us1[64][136]; } st;
    struct { float A[2][64][64]; float lA[2][2][64]; } red;
  } sm;
  // XCD-clustered decode: f -> xcd = f&7 (dispatch round-robin); XCD x owns
  // heads [4x,4x+4) x all 16 q-tiles.  Bijective: f = ((hidx&3)*16+qt)*8+xcd.
  const int f = blockIdx.x;              // 0..511
  const int xcd = f & 7;
  const int j = f >> 3;                  // 0..63
  const int qt = j & 15;
  const int hidx = xcd * 4 + (j >> 4);   // 0..31
  const int h = hidx & 7, nb = hidx >> 3;
  const int q0 = qt * 128;
  const int tid = threadIdx.x;
  const int lane = tid & 63;
  const int w = tid >> 6;           // wave 0..3
  const int wv = w & 1;             // q-half of the block tile
  const int sg = w >> 1;            // s-group 0..1
  const int lm = lane & 31;
  const int kg = lane >> 5;         // k-group within MFMA operands
  const int srow = tid >> 1;        // K staging row 0..127
  const int scb = (tid & 1) * 32;   // K staging col base (fp16 units)
  const int urow = tid >> 2;        // U staging row (d) 0..63
  const int ucb = (tid & 3) * 32;   // U staging col base (s units)
  const size_t headbase = ((size_t)nb * N_HEADS + h) * L_SEQ;
  const size_t dbase = ((size_t)nb * N_HEADS + h) * H_DIM;

  // hoist Q B-frags straight from global (no Q LDS): q(nt) = q0+wv*64+nt*32+lm
  f16x8 bq[2][4];
#pragma unroll
  for (int nt = 0; nt < 2; ++nt)
#pragma unroll
    for (int kc = 0; kc < 4; ++kc)
      bq[nt][kc] = *(const f16x8*)(qbuf +
          (headbase + q0 + wv * 64 + nt * 32 + lm) * H_DIM + kc * 16 + kg * 8);

  f32x16 o[2][2];  // [q-half nt][d-half mt2]
  o[0][0] = (f32x16)(0.f); o[0][1] = (f32x16)(0.f);
  o[1][0] = (f32x16)(0.f); o[1][1] = (f32x16)(0.f);
  float lsum[2] = {0.f, 0.f};

  // compute one 64-row s-slice from a staged half-tile
  auto do_half = [&](const _Float16 (&Ks)[128][72], const _Float16 (&Us)[64][136]) {
    const int sr = sg * 64;  // this wave's s-rows within the staged 128

    // ---- S^T: sc[nt][mt], C-layout row = s_local, col = q (lane&31) ----
    f32x16 sc[2][2];
    sc[0][0] = (f32x16)(0.f); sc[0][1] = (f32x16)(0.f);
    sc[1][0] = (f32x16)(0.f); sc[1][1] = (f32x16)(0.f);
    __builtin_amdgcn_s_setprio(1);
#pragma unroll
    for (int kc = 0; kc < 4; ++kc) {
      const f16x8 ak0 = *(const f16x8*)&Ks[sr + lm][kc * 16 + kg * 8];
      const f16x8 ak1 = *(const f16x8*)&Ks[sr + 32 + lm][kc * 16 + kg * 8];
      sc[0][0] = __builtin_amdgcn_mfma_f32_32x32x16_f16(ak0, bq[0][kc], sc[0][0], 0, 0, 0);
      sc[0][1] = __builtin_amdgcn_mfma_f32_32x32x16_f16(ak1, bq[0][kc], sc[0][1], 0, 0, 0);
      sc[1][0] = __builtin_amdgcn_mfma_f32_32x32x16_f16(ak0, bq[1][kc], sc[1][0], 0, 0, 0);
      sc[1][1] = __builtin_amdgcn_mfma_f32_32x32x16_f16(ak1, bq[1][kc], sc[1][1], 0, 0, 0);
    }
    __builtin_amdgcn_s_setprio(0);

    // ---- p = exp2(score); pack fp16 pairs; per-lane l partial sum ----
    unsigned int P2[2][2][4][2];
#pragma unroll
    for (int nt = 0; nt < 2; ++nt)
#pragma unroll
      for (int mt = 0; mt < 2; ++mt)
#pragma unroll
        for (int g = 0; g < 4; ++g) {
          const float p0 = __builtin_amdgcn_exp2f(sc[nt][mt][4 * g + 0]);
          const float p1 = __builtin_amdgcn_exp2f(sc[nt][mt][4 * g + 1]);
          const float p2 = __builtin_amdgcn_exp2f(sc[nt][mt][4 * g + 2]);
          const float p3 = __builtin_amdgcn_exp2f(sc[nt][mt][4 * g + 3]);
          lsum[nt] += (p0 + p1) + (p2 + p3);
          P2[nt][mt][g][0] = packf16(p0, p1);
          P2[nt][mt][g][1] = packf16(p2, p3);
        }

    // ---- PV: O^T += U^T @ P^T; P B-frags via permlane32_swap (T12).
    //      v_permlane32_swap_b32 a,b: a[32..63] <-> b[0..31].  With
    //      a=x0,b=y0: a' = (l<32 ? x0[l] : y0[l-32]) == old bp.u[0];
    //      b' = (l<32 ? x0[l+32] : y0[l]) == old bp.u[2].  Bit-identical
    //      to the shfl_xor+cndmask network it replaces. ----
    __builtin_amdgcn_s_setprio(1);
#pragma unroll
    for (int kc = 0; kc < 4; ++kc) {
      const int mt = kc >> 1;
      const f16x8 au0 = *(const f16x8*)&Us[lm][sr + kc * 16 + kg * 8];
      const f16x8 au1 = *(const f16x8*)&Us[32 + lm][sr + kc * 16 + kg * 8];
#pragma unroll
      for (int nt = 0; nt < 2; ++nt) {
        const int gx = (2 * kc) & 3, gy = (2 * kc + 1) & 3;
        unsigned int a0 = P2[nt][mt][gx][0], b0 = P2[nt][mt][gy][0];
        unsigned int a1 = P2[nt][mt][gx][1], b1 = P2[nt][mt][gy][1];
        asm("v_permlane32_swap_b32 %0, %1" : "+v"(a0), "+v"(b0));
        asm("v_permlane32_swap_b32 %0, %1" : "+v"(a1), "+v"(b1));
        union { unsigned int u[4]; f16x8 v; } bp;
        bp.u[0] = a0;  // j0..3: s = kc*16+kg*8+0..3
        bp.u[1] = a1;
        bp.u[2] = b0;  // j4..7: s = kc*16+kg*8+4..7
        bp.u[3] = b1;
        o[nt][0] = __builtin_amdgcn_mfma_f32_32x32x16_f16(au0, bp.v, o[nt][0], 0, 0, 0);
        o[nt][1] = __builtin_amdgcn_mfma_f32_32x32x16_f16(au1, bp.v, o[nt][1], 0, 0, 0);
      }
    }
    __builtin_amdgcn_s_setprio(0);
  };

  for (int it = 0; it < 8; ++it) {
    const int s0 = it * 256;
    __syncthreads();  // B1: prior window's frag reads complete
    {
      const _Float16* kp = kbuf + (headbase + s0 + srow) * H_DIM + scb;
      *(uint4*)&sm.st.Ks0[srow][scb + 0]  = ((const uint4*)kp)[0];
      *(uint4*)&sm.st.Ks0[srow][scb + 8]  = ((const uint4*)kp)[1];
      *(uint4*)&sm.st.Ks0[srow][scb + 16] = ((const uint4*)kp)[2];
      *(uint4*)&sm.st.Ks0[srow][scb + 24] = ((const uint4*)kp)[3];
      const _Float16* kq = kbuf + (headbase + s0 + 128 + srow) * H_DIM + scb;
      *(uint4*)&sm.st.Ks1[srow][scb + 0]  = ((const uint4*)kq)[0];
      *(uint4*)&sm.st.Ks1[srow][scb + 8]  = ((const uint4*)kq)[1];
      *(uint4*)&sm.st.Ks1[srow][scb + 16] = ((const uint4*)kq)[2];
      *(uint4*)&sm.st.Ks1[srow][scb + 24] = ((const uint4*)kq)[3];
      const _Float16* up = uT + (dbase + urow) * L_SEQ + s0 + ucb;
      *(uint4*)&sm.st.Us0[urow][ucb + 0]  = ((const uint4*)up)[0];
      *(uint4*)&sm.st.Us0[urow][ucb + 8]  = ((const uint4*)up)[1];
      *(uint4*)&sm.st.Us0[urow][ucb + 16] = ((const uint4*)up)[2];
      *(uint4*)&sm.st.Us0[urow][ucb + 24] = ((const uint4*)up)[3];
      const _Float16* uq = up + 128;
      *(uint4*)&sm.st.Us1[urow][ucb + 0]  = ((const uint4*)uq)[0];
      *(uint4*)&sm.st.Us1[urow][ucb + 8]  = ((const uint4*)uq)[1];
      *(uint4*)&sm.st.Us1[urow][ucb + 16] = ((const uint4*)uq)[2];
      *(uint4*)&sm.st.Us1[urow][ucb + 24] = ((const uint4*)uq)[3];
    }
    __syncthreads();  // B2: staged 256-row tile visible to all waves

    do_half(sm.st.Ks0, sm.st.Us0);
    do_half(sm.st.Ks1, sm.st.Us1);
  }

  // ---- cross-s-group reduction in LDS: sg1 publishes (o, lsum), sg0
  //      accumulates.  XOR-swizzled float4 slots keep accesses at the
  //      8-dwords/bank wave64 minimum (conflict-free).  ----
  float* redA = &sm.red.A[0][0][0];
  float* lrA = &sm.red.lA[0][0][0];

  __syncthreads();  // loop's trailing frag reads complete before LDS reuse
  if (sg == 1) {
#pragma unroll
    for (int nt = 0; nt < 2; ++nt) {
      lrA[(wv * 2 + nt) * 64 + lane] = lsum[nt];
#pragma unroll
      for (int mt2 = 0; mt2 < 2; ++mt2)
#pragma unroll
        for (int g = 0; g < 4; ++g) {
          const int i4 = ((nt * 2 + mt2) * 4 + g) ^ (lane & 7);
          float4 v = {o[nt][mt2][4 * g + 0], o[nt][mt2][4 * g + 1],
                      o[nt][mt2][4 * g + 2], o[nt][mt2][4 * g + 3]};
          *(float4*)(redA + ((size_t)(wv * 64 + lane)) * 64 + i4 * 4) = v;
        }
    }
  }
  __syncthreads();
  if (sg == 1) return;  // sg0 past this point; no further barriers
#pragma unroll
  for (int nt = 0; nt < 2; ++nt) {
    lsum[nt] += lrA[(wv * 2 + nt) * 64 + lane];
#pragma unroll
    for (int mt2 = 0; mt2 < 2; ++mt2)
#pragma unroll
      for (int g = 0; g < 4; ++g) {
        const int i4 = ((nt * 2 + mt2) * 4 + g) ^ (lane & 7);
        const float4 v =
            *(const float4*)(redA + ((size_t)(wv * 64 + lane)) * 64 + i4 * 4);
        o[nt][mt2][4 * g + 0] += v.x; o[nt][mt2][4 * g + 1] += v.y;
        o[nt][mt2][4 * g + 2] += v.z; o[nt][mt2][4 * g + 3] += v.w;
      }
  }

  // ---- epilogue: finish l across kg halves, GeM inverse, packed stores ----
#pragma unroll
  for (int nt = 0; nt < 2; ++nt) {
    const float l = lsum[nt] + __shfl_xor(lsum[nt], 32);
    const float inv = 1.0f / l;
    const int qg = q0 + wv * 64 + nt * 32 + lm;
    const size_t base = ((size_t)qg * N_BATCH + nb) * E_DIM + h * H_DIM;
#pragma unroll
    for (int mt2 = 0; mt2 < 2; ++mt2)
#pragma unroll
      for (int g = 0; g < 4; ++g) {
        alignas(8) __hip_bfloat16 hb[4], lb[4];
#pragma unroll
        for (int i = 0; i < 4; ++i) {
          const int d = mt2 * 32 + 8 * g + 4 * kg + i;
          const int e = h * H_DIM + d;
          const float pooled = o[nt][mt2][4 * g + i] * inv;
          const float val = __powf(fmaxf(pooled, EPS_F), 1.0f / pw[e]) - sw[e];
          split2(val, hb[i], lb[i]);
        }
        const int d0 = mt2 * 32 + 8 * g + 4 * kg;
        *(uint2*)(ohhi + base + d0) = *(const uint2*)hb;
        *(uint2*)(ohlo + base + d0) = *(const uint2*)lb;
      }
  }
}

// ---------------------------------------------------------------------------
// Kernel C: output projection via MFMA, hi/lo 3-pass.  (unchanged)
// ---------------------------------------------------------------------------
__global__ __launch_bounds__(256, 4) void out_proj_kernel(
    const __hip_bfloat16* __restrict__ xhi, const __hip_bfloat16* __restrict__ xlo,
    const __hip_bfloat16* __restrict__ whi, const __hip_bfloat16* __restrict__ wlo,
    const float* __restrict__ bias, float* __restrict__ out) {
  __shared__ __hip_bfloat16 Xh[128][40];
  __shared__ __hip_bfloat16 Xl[128][40];
  __shared__ __hip_bfloat16 Wh[64][40];
  __shared__ __hip_bfloat16 Wl[64][40];
  const int row0 = blockIdx.x * 128;
  const int col0 = blockIdx.y * 64;
  const int tid = threadIdx.x;
  const int lane = tid & 63;
  const int wv = tid >> 6;
  const int lidx = lane & 15;
  const int quad = lane >> 4;
  const int srow = tid >> 1;
  const int scol = (tid & 1) * 16;
  const int wrow = tid >> 2;
  const int wcol = (tid & 3) * 8;

  f32x4 acc[2][4];
#pragma unroll
  for (int rt = 0; rt < 2; ++rt)
#pragma unroll
    for (int ct = 0; ct < 4; ++ct) acc[rt][ct] = (f32x4){0.f, 0.f, 0.f, 0.f};

  const int ar0 = wv * 32 + lidx;

  for (int kt = 0; kt < 16; ++kt) {
    const int k0 = kt * 32;
    {
      const size_t xof = (size_t)(row0 + srow) * E_DIM + k0 + scol;
      *(uint4*)&Xh[srow][scol]     = ((const uint4*)(xhi + xof))[0];
      *(uint4*)&Xh[srow][scol + 8] = ((const uint4*)(xhi + xof))[1];
      *(uint4*)&Xl[srow][scol]     = ((const uint4*)(xlo + xof))[0];
      *(uint4*)&Xl[srow][scol + 8] = ((const uint4*)(xlo + xof))[1];
      const size_t wof = (size_t)(col0 + wrow) * E_DIM + k0 + wcol;
      *(uint4*)&Wh[wrow][wcol] = *(const uint4*)(whi + wof);
      *(uint4*)&Wl[wrow][wcol] = *(const uint4*)(wlo + wof);
    }
    __syncthreads();

    const bf16x8 ah0 = *(const bf16x8*)&Xh[ar0][quad * 8];
    const bf16x8 ah1 = *(const bf16x8*)&Xh[ar0 + 16][quad * 8];
    const bf16x8 al0 = *(const bf16x8*)&Xl[ar0][quad * 8];
    const bf16x8 al1 = *(const bf16x8*)&Xl[ar0 + 16][quad * 8];
#pragma unroll
    for (int ct = 0; ct < 4; ++ct) {
      const bf16x8 bh = *(const bf16x8*)&Wh[ct * 16 + lidx][quad * 8];
      const bf16x8 bl = *(const bf16x8*)&Wl[ct * 16 + lidx][quad * 8];
      acc[0][ct] = __builtin_amdgcn_mfma_f32_16x16x32_bf16(ah0, bh, acc[0][ct], 0, 0, 0);
      acc[0][ct] = __builtin_amdgcn_mfma_f32_16x16x32_bf16(al0, bh, acc[0][ct], 0, 0, 0);
      acc[0][ct] = __builtin_amdgcn_mfma_f32_16x16x32_bf16(ah0, bl, acc[0][ct], 0, 0, 0);
      acc[1][ct] = __builtin_amdgcn_mfma_f32_16x16x32_bf16(ah1, bh, acc[1][ct], 0, 0, 0);
      acc[1][ct] = __builtin_amdgcn_mfma_f32_16x16x32_bf16(al1, bh, acc[1][ct], 0, 0, 0);
      acc[1][ct] = __builtin_amdgcn_mfma_f32_16x16x32_bf16(ah1, bl, acc[1][ct], 0, 0, 0);
    }
    __syncthreads();
  }

  float bv[4];
#pragma unroll
  for (int ct = 0; ct < 4; ++ct) bv[ct] = bias[col0 + ct * 16 + lidx];
#pragma unroll
  for (int rt = 0; rt < 2; ++rt)
#pragma unroll
    for (int ct = 0; ct < 4; ++ct) {
      const int c = col0 + ct * 16 + lidx;
#pragma unroll
      for (int reg = 0; reg < 4; ++reg) {
        const int R = row0 + wv * 32 + rt * 16 + quad * 4 + reg;
        out[(size_t)R * E_DIM + c] = acc[rt][ct][reg] + bv[ct];
      }
    }
}

extern "C" void kernel_launch(void* const* d_in, const int* in_sizes, int n_in,
                              void* d_out, int out_size, void* d_ws, size_t ws_size,
                              hipStream_t stream) {
  const float* q_in = (const float*)d_in[0];
  const float* k_in = (const float*)d_in[1];
  const float* v_in = (const float*)d_in[2];
  const float* wio  = (const float*)d_in[3];
  const float* bio  = (const float*)d_in[4];
  const float* wo   = (const float*)d_in[5];
  const float* bo   = (const float*)d_in[6];
  const float* pw   = (const float*)d_in[7];
  const float* sw   = (const float*)d_in[8];

  // Workspace layout unchanged (ubuf region now holds fp16 u in its first
  // half; ohhi/ohlo alias it after transp consumes u).
  const size_t NE = (size_t)N_ROWS * E_DIM;
  _Float16* qbuf = (_Float16*)d_ws;
  _Float16* kbuf = qbuf + NE;
  float* ubuf = (float*)(kbuf + NE);
  _Float16* uT = (_Float16*)(ubuf + NE);
  __hip_bfloat16* wiohi = (__hip_bfloat16*)(uT + NE);
  __hip_bfloat16* wiolo = wiohi + 786432;
  __hip_bfloat16* wohi  = wiolo + 786432;
  __hip_bfloat16* wolo  = wohi + 262144;
  __hip_bfloat16* ohhi = (__hip_bfloat16*)ubuf;  // alias: ubuf dead after transp
  __hip_bfloat16* ohlo = ohhi + NE;

  wconv_kernel<<<dim3(1024), 256, 0, stream>>>(wio, wo, wiohi, wiolo, wohi, wolo);
  proj_qkv_kernel<<<dim3(64, 4, 3), 256, 0, stream>>>(q_in, k_in, v_in, wiohi,
                                                      bio, pw, sw, qbuf, kbuf,
                                                      (_Float16*)ubuf);
  transp_kernel<<<dim3(32, 8, 4), 256, 0, stream>>>((const _Float16*)ubuf, uT);
  attn_kernel<<<dim3(512), 256, 0, stream>>>(qbuf, kbuf, uT, pw, sw,
                                             ohhi, ohlo);
  out_proj_kernel<<<dim3(64, 8), 256, 0, stream>>>(ohhi, ohlo, wohi, wolo,
                                                   bo, (float*)d_out);
}